// Round 3
// baseline (21455.754 us; speedup 1.0000x reference)
//
#include <hip/hip_runtime.h>
#include <cstdint>
#include <cstddef>

#define DEV static __device__ __forceinline__

typedef short bf16x8 __attribute__((ext_vector_type(8)));
typedef float f32x4 __attribute__((ext_vector_type(4)));
typedef unsigned short u16;

DEV float wredf(float v) {
  v += __shfl_xor(v, 32, 64); v += __shfl_xor(v, 16, 64);
  v += __shfl_xor(v, 8, 64);  v += __shfl_xor(v, 4, 64);
  v += __shfl_xor(v, 2, 64);  v += __shfl_xor(v, 1, 64);
  return v;
}

DEV void ld4(float* d, const float* p) {
  float4 t = *(const float4*)p;
  d[0] = t.x; d[1] = t.y; d[2] = t.z; d[3] = t.w;
}
DEV void st4(float* p, const float* s) {
  *(float4*)p = make_float4(s[0], s[1], s[2], s[3]);
}

// round-to-nearest-even fp32 -> bf16 bits
DEV unsigned int bfh16(float v) {
  unsigned int u = __float_as_uint(v);
  return (u + 0x7FFFu + ((u >> 16) & 1u)) >> 16;
}
// split pair (a,b) -> packed hi-word / lo-word (2x bf16 each)
DEV uint2 splitpk(float a, float b) {
  unsigned int ha = bfh16(a), hb = bfh16(b);
  float la = a - __uint_as_float(ha << 16);
  float lb = b - __uint_as_float(hb << 16);
  return make_uint2(ha | (hb << 16), bfh16(la) | (bfh16(lb) << 16));
}

// ---- embed: src = [x,t] @ emb_W + emb_b  (fp32) --------------------------
__global__ __launch_bounds__(256)
void embed_kernel(const float* __restrict__ x, const float* __restrict__ t,
                  const float* __restrict__ W, const float* __restrict__ eb,
                  float* __restrict__ X) {
  const int gid = blockIdx.x * 256 + threadIdx.x;  // R*64
  const int row = gid >> 6, d = (gid & 63) * 8;
  const float xv = x[row], tv = t[row];
  #pragma unroll
  for (int j = 0; j < 8; j++)
    X[(size_t)row * 512 + d + j] =
        xv * W[d + j] + tv * W[512 + d + j] + eb[d + j];
}

// ---- layernorm row=512, fp32 -> split bf16 hi/lo planes ------------------
__global__ __launch_bounds__(256)
void ln_split(const float* __restrict__ X, const float* __restrict__ w,
              const float* __restrict__ bb, u16* __restrict__ hi,
              u16* __restrict__ lo) {
  const int row = blockIdx.x * 4 + (threadIdx.x >> 6);
  const int lane = threadIdx.x & 63;
  const float* xp = X + (size_t)row * 512 + lane * 8;
  float4 a0 = *(const float4*)xp;
  float4 a1 = *(const float4*)(xp + 4);
  float v[8] = {a0.x, a0.y, a0.z, a0.w, a1.x, a1.y, a1.z, a1.w};
  float s = 0.f, sq = 0.f;
  #pragma unroll
  for (int j = 0; j < 8; j++) { s += v[j]; sq += v[j] * v[j]; }
  s = wredf(s); sq = wredf(sq);
  const float mean = s * (1.f / 512.f);
  const float var = fmaxf(sq * (1.f / 512.f) - mean * mean, 0.f);
  const float inv = rsqrtf(var + 1e-5f);
  const float* wp = w + lane * 8;
  const float* bp = bb + lane * 8;
  float o[8];
  #pragma unroll
  for (int j = 0; j < 8; j++)
    o[j] = (v[j] - mean) * inv * wp[j] + bp[j];
  uint2 p0 = splitpk(o[0], o[1]), p1 = splitpk(o[2], o[3]);
  uint2 p2 = splitpk(o[4], o[5]), p3 = splitpk(o[6], o[7]);
  const size_t off = (size_t)row * 512 + lane * 8;
  *(int4*)(hi + off) = make_int4(p0.x, p1.x, p2.x, p3.x);
  *(int4*)(lo + off) = make_int4(p0.y, p1.y, p2.y, p3.y);
}

// ---- fused attention: xpos+decay staging, causal retention, groupnorm ----
// Block: 64 q-rows x 1 head. QKV row: [Q(512) K(512) V(1024)] raw (unrotated).
// Rotation/scale/decay applied while staging Q/K into LDS. Epilogue fuses
// group-norm over the 128 v-dims (16-lane shfl reduction) + affine.
__global__ __launch_bounds__(256)
void attn_fused(const float* __restrict__ QKV, float* __restrict__ Y,
                const float* __restrict__ gw, const float* __restrict__ gb) {
  __shared__ float Qs[64][68];   // [e][s]
  __shared__ float Ks[64][68];   // [e][m]
  __shared__ float At[64][68];   // [m][s]
  const int h = blockIdx.y;
  const int r0 = blockIdx.x * 64;       // chunk-local first row
  const int b = r0 >> 8;
  const int s0 = r0 & 255;
  const int st = s0 >> 6;               // diagonal m-tile index
  const int tid = threadIdx.x;
  const int ty = tid >> 4, tx = tid & 15;

  const float l32 = logf(1.0f / 32.0f), l512 = logf(1.0f / 512.0f);
  const float gamma = 1.0f - expf(l32 + (float)h * (l512 - l32) / 7.0f);

  const int rr = tid >> 2, e0 = (tid & 3) * 16;
  // per-pair invariants for this thread's 8 pairs
  float svp[8], invf[8];
  #pragma unroll
  for (int j = 0; j < 8; j++) {
    const int i = (e0 >> 1) + j;
    svp[j] = (2.0f * i + 25.6f) / 89.6f;
    invf[j] = powf(10000.0f, -(float)i * (1.0f / 32.0f));
  }

  {  // stage Q transposed, rotated, *gamma^s * scale
    const float fs = (float)((r0 + rr) & 255);
    const float gq = powf(gamma, fs);
    const float* qp = QKV + (size_t)(r0 + rr) * 2048 + h * 64 + e0;
    #pragma unroll
    for (int j = 0; j < 8; j++) {
      const float sc = powf(svp[j], fs * (1.0f / 512.0f));
      const float ang = fs * invf[j];
      const float f = sc * gq;
      const float c = cosf(ang) * f, sg = sinf(ang) * f;
      const float v0 = qp[2 * j], v1 = qp[2 * j + 1];
      Qs[e0 + 2 * j][rr]     = v0 * c - v1 * sg;
      Qs[e0 + 2 * j + 1][rr] = v1 * c + v0 * sg;
    }
  }

  float acc2[4][8];
  #pragma unroll
  for (int i = 0; i < 4; i++)
    #pragma unroll
    for (int j = 0; j < 8; j++) acc2[i][j] = 0.f;

  for (int mt = 0; mt <= st; mt++) {
    const int m0 = mt * 64;
    {  // stage K tile transposed, rotated, *gamma^-m / scale
      const float fm = (float)(m0 + rr);
      const float gk = powf(gamma, fm);
      const float* kp = QKV + (size_t)(b * 256 + m0 + rr) * 2048 + 512 + h * 64 + e0;
      #pragma unroll
      for (int j = 0; j < 8; j++) {
        const float sc = powf(svp[j], fm * (1.0f / 512.0f));
        const float ang = fm * invf[j];
        const float f = 1.0f / (sc * gk);
        const float c = cosf(ang) * f, sg = sinf(ang) * f;
        const float v0 = kp[2 * j], v1 = kp[2 * j + 1];
        Ks[e0 + 2 * j][rr]     = v0 * c - v1 * sg;
        Ks[e0 + 2 * j + 1][rr] = v1 * c + v0 * sg;
      }
    }
    __syncthreads();
    float a1[4][4];
    #pragma unroll
    for (int i = 0; i < 4; i++)
      #pragma unroll
      for (int j = 0; j < 4; j++) a1[i][j] = 0.f;
    #pragma unroll 4
    for (int e = 0; e < 64; e++) {
      float qa[4], kb[4];
      ld4(qa, &Qs[e][ty * 4]);
      ld4(kb, &Ks[e][tx * 4]);
      #pragma unroll
      for (int i = 0; i < 4; i++)
        #pragma unroll
        for (int j = 0; j < 4; j++)
          a1[i][j] = fmaf(qa[i], kb[j], a1[i][j]);
    }
    #pragma unroll
    for (int i = 0; i < 4; i++)
      #pragma unroll
      for (int j = 0; j < 4; j++) {
        float v = a1[i][j];
        if (mt == st && (m0 + tx * 4 + j) > (s0 + ty * 4 + i)) v = 0.f;
        At[tx * 4 + j][ty * 4 + i] = v;
      }
    __syncthreads();
    const float* vp = QKV + (size_t)(b * 256 + m0) * 2048 + 1024 + h * 128 + tx * 8;
    #pragma unroll 4
    for (int m = 0; m < 64; m++) {
      float av[4], vv[8];
      ld4(av, &At[m][ty * 4]);
      ld4(vv, vp);
      ld4(vv + 4, vp + 4);
      vp += 2048;
      #pragma unroll
      for (int i = 0; i < 4; i++)
        #pragma unroll
        for (int j = 0; j < 8; j++)
          acc2[i][j] = fmaf(av[i], vv[j], acc2[i][j]);
    }
    __syncthreads();
  }

  // fused group-norm epilogue: per row, reduce over the 16-lane tx group
  const int vi = h * 128 + tx * 8;
  float gwv[8], gbv[8];
  ld4(gwv, gw + vi); ld4(gwv + 4, gw + vi + 4);
  ld4(gbv, gb + vi); ld4(gbv + 4, gb + vi + 4);
  #pragma unroll
  for (int i = 0; i < 4; i++) {
    float s = 0.f, sq = 0.f;
    #pragma unroll
    for (int j = 0; j < 8; j++) { s += acc2[i][j]; sq += acc2[i][j] * acc2[i][j]; }
    #pragma unroll
    for (int msk = 1; msk <= 8; msk <<= 1) {
      s += __shfl_xor(s, msk, 64);
      sq += __shfl_xor(sq, msk, 64);
    }
    const float mean = s * (1.f / 128.f);
    const float var = fmaxf(sq * (1.f / 128.f) - mean * mean, 0.f);
    const float inv = rsqrtf(var + 1e-5f);
    float o[8];
    #pragma unroll
    for (int j = 0; j < 8; j++)
      o[j] = (acc2[i][j] - mean) * inv * gwv[j] + gbv[j];
    float* yp = Y + (size_t)(r0 + ty * 4 + i) * 1024 + vi;
    st4(yp, o);
    st4(yp + 4, o + 4);
  }
}

// ---- final N=1 dot (fp32) ------------------------------------------------
__global__ __launch_bounds__(256)
void head3_kernel(const float* __restrict__ X, const float* __restrict__ w,
                  const float* __restrict__ b3, float* __restrict__ out) {
  const int row = blockIdx.x * 4 + (threadIdx.x >> 6);
  const int lane = threadIdx.x & 63;
  const float* xp = X + (size_t)row * 512 + lane * 8;
  const float* wp = w + lane * 8;
  float s = 0.f;
  #pragma unroll
  for (int j = 0; j < 8; j++) s += xp[j] * wp[j];
  s = wredf(s);
  if (lane == 0) out[row] = s + b3[0];
}

// ---- weight pre-pack: W[K][N] (fp32) -> Bt_hi/Bt_lo [N][K] (bf16) --------
__global__ __launch_bounds__(256)
void pack_plain(const float* __restrict__ W, u16* __restrict__ hi,
                u16* __restrict__ lo, int N, int kshift) {
  const int idx = blockIdx.x * 256 + threadIdx.x;   // n*K + k
  const int K = 1 << kshift;
  const int n = idx >> kshift, k = idx & (K - 1);
  const float v = W[(size_t)k * N + n];
  const unsigned int h = bfh16(v);
  const float l = v - __uint_as_float(h << 16);
  hi[idx] = (u16)h;
  lo[idx] = (u16)bfh16(l);
}

// QKV head-interleaved mapping: col c<512 -> WQ(h,k,e), <1024 -> WK, else WV
__global__ __launch_bounds__(256)
void pack_qkv(const float* __restrict__ WQ, const float* __restrict__ WK,
              const float* __restrict__ WV, u16* __restrict__ hi,
              u16* __restrict__ lo) {
  const int idx = blockIdx.x * 256 + threadIdx.x;   // c*512 + k
  const int c = idx >> 9, k = idx & 511;
  float v;
  if (c < 512)
    v = WQ[((size_t)(c >> 6) * 512 + k) * 64 + (c & 63)];
  else if (c < 1024)
    v = WK[((size_t)((c - 512) >> 6) * 512 + k) * 64 + ((c - 512) & 63)];
  else
    v = WV[((size_t)((c - 1024) >> 7) * 512 + k) * 128 + ((c - 1024) & 127)];
  const unsigned int h = bfh16(v);
  const float l = v - __uint_as_float(h << 16);
  hi[idx] = (u16)h;
  lo[idx] = (u16)bfh16(l);
}

// ---- bf16x3 MFMA GEMM: C(MxN) = A(MxK) @ B(KxN) + epilogue ---------------
// AMODE 0: A fp32 [M][K], split in-kernel.  AMODE 1: A pre-split hi/lo bf16.
// B pre-packed [N][K] hi/lo.  128x128 tile, BK=32, 4 waves, 4x4 16x16x32.
// acc += ah*bh + ah*bl + al*bh.  LDS rows padded to 40 shorts (2-way max).
// EPI 0: store    1: silu(acc)*aux     2: acc+aux
//     3: gelu(acc+bias)   4: acc+bias+aux   5: w0*sin(acc+b)+w1*cos(acc+b)
// OSPLIT 0: fp32 C.  1: split bf16 hi/lo planes Ch/Cl.
template<int EPI, int AMODE, int OSPLIT>
__global__ __launch_bounds__(256, 2)
void gemm_mfma(const float* __restrict__ Af, const u16* __restrict__ Agh,
               const u16* __restrict__ Agl, const u16* __restrict__ Bh,
               const u16* __restrict__ Bl, float* __restrict__ C,
               u16* __restrict__ Ch, u16* __restrict__ Cl,
               const int N, const int K,
               const float* __restrict__ bias, const float* __restrict__ aux,
               const float* __restrict__ wave2) {
  __shared__ __align__(16) u16 Ah[128][40];
  __shared__ __align__(16) u16 Al[128][40];
  __shared__ __align__(16) u16 Bhs[128][40];
  __shared__ __align__(16) u16 Bls[128][40];
  const int tid = threadIdx.x;
  const int lane = tid & 63;
  const int wave = tid >> 6;
  const int wr = (wave >> 1) * 64, wc = (wave & 1) * 64;
  const int m0 = blockIdx.y * 128, n0 = blockIdx.x * 128;

  const int ar = tid >> 1;             // 0..127 : A row within tile
  const int aks = (tid & 1) * 16;      // 0/16   : A k sub-offset (elements)
  const int bu = tid & 127;
  const u16* Bp = ((tid >> 7) ? Bl : Bh) + (size_t)(n0 + bu) * K;
  u16* Bw = ((tid >> 7) ? &Bls[0][0] : &Bhs[0][0]) + bu * 40;

  const int fm = lane & 15;
  const int fkb = (lane >> 4) * 16;    // byte offset of this lane's k-slice

  f32x4 acc[4][4];
  #pragma unroll
  for (int i = 0; i < 4; i++)
    #pragma unroll
    for (int j = 0; j < 4; j++)
      acc[i][j] = (f32x4){0.f, 0.f, 0.f, 0.f};

  // --- staging state ---
  const float* Ap = nullptr;
  const u16 *Ahp = nullptr, *Alp = nullptr;
  float a_reg[16];
  int4 ah_reg[2], al_reg[2], b_reg[4];

  if constexpr (AMODE == 0) {
    Ap = Af + (size_t)(m0 + ar) * K + aks;
    ld4(a_reg, Ap);        ld4(a_reg + 4, Ap + 4);
    ld4(a_reg + 8, Ap + 8); ld4(a_reg + 12, Ap + 12);
  } else {
    Ahp = Agh + (size_t)(m0 + ar) * K + aks;
    Alp = Agl + (size_t)(m0 + ar) * K + aks;
    ah_reg[0] = *(const int4*)(Ahp);
    ah_reg[1] = *(const int4*)(Ahp + 8);
    al_reg[0] = *(const int4*)(Alp);
    al_reg[1] = *(const int4*)(Alp + 8);
  }
  #pragma unroll
  for (int i = 0; i < 4; i++) b_reg[i] = *(const int4*)(Bp + i * 8);

  for (int kt = 0; kt < K; kt += 32) {
    if constexpr (AMODE == 0) {  // split + write A
      uint2 q0 = splitpk(a_reg[0], a_reg[1]);
      uint2 q1 = splitpk(a_reg[2], a_reg[3]);
      uint2 q2 = splitpk(a_reg[4], a_reg[5]);
      uint2 q3 = splitpk(a_reg[6], a_reg[7]);
      uint2 q4 = splitpk(a_reg[8], a_reg[9]);
      uint2 q5 = splitpk(a_reg[10], a_reg[11]);
      uint2 q6 = splitpk(a_reg[12], a_reg[13]);
      uint2 q7 = splitpk(a_reg[14], a_reg[15]);
      *(int4*)&Ah[ar][aks]     = make_int4(q0.x, q1.x, q2.x, q3.x);
      *(int4*)&Ah[ar][aks + 8] = make_int4(q4.x, q5.x, q6.x, q7.x);
      *(int4*)&Al[ar][aks]     = make_int4(q0.y, q1.y, q2.y, q3.y);
      *(int4*)&Al[ar][aks + 8] = make_int4(q4.y, q5.y, q6.y, q7.y);
    } else {
      *(int4*)&Ah[ar][aks]     = ah_reg[0];
      *(int4*)&Ah[ar][aks + 8] = ah_reg[1];
      *(int4*)&Al[ar][aks]     = al_reg[0];
      *(int4*)&Al[ar][aks + 8] = al_reg[1];
    }
    *(int4*)&Bw[0]  = b_reg[0];
    *(int4*)&Bw[8]  = b_reg[1];
    *(int4*)&Bw[16] = b_reg[2];
    *(int4*)&Bw[24] = b_reg[3];
    __syncthreads();
    if (kt + 32 < K) {  // prefetch next tile into regs (spans MFMA phase)
      if constexpr (AMODE == 0) {
        const float* ap = Ap + kt + 32;
        ld4(a_reg, ap);        ld4(a_reg + 4, ap + 4);
        ld4(a_reg + 8, ap + 8); ld4(a_reg + 12, ap + 12);
      } else {
        ah_reg[0] = *(const int4*)(Ahp + kt + 32);
        ah_reg[1] = *(const int4*)(Ahp + kt + 40);
        al_reg[0] = *(const int4*)(Alp + kt + 32);
        al_reg[1] = *(const int4*)(Alp + kt + 40);
      }
      const u16* bp = Bp + kt + 32;
      #pragma unroll
      for (int i = 0; i < 4; i++) b_reg[i] = *(const int4*)(bp + i * 8);
    }
    bf16x8 avh[4], avl[4];
    #pragma unroll
    for (int mf = 0; mf < 4; mf++) {
      const int m = wr + mf * 16 + fm;
      avh[mf] = *(const bf16x8*)((const char*)&Ah[m][0] + fkb);
      avl[mf] = *(const bf16x8*)((const char*)&Al[m][0] + fkb);
    }
    #pragma unroll
    for (int nf = 0; nf < 4; nf++) {
      const int n = wc + nf * 16 + fm;
      bf16x8 bh = *(const bf16x8*)((const char*)&Bhs[n][0] + fkb);
      bf16x8 bl = *(const bf16x8*)((const char*)&Bls[n][0] + fkb);
      #pragma unroll
      for (int mf = 0; mf < 4; mf++) {
        acc[mf][nf] = __builtin_amdgcn_mfma_f32_16x16x32_bf16(avh[mf], bh, acc[mf][nf], 0, 0, 0);
        acc[mf][nf] = __builtin_amdgcn_mfma_f32_16x16x32_bf16(avl[mf], bh, acc[mf][nf], 0, 0, 0);
        acc[mf][nf] = __builtin_amdgcn_mfma_f32_16x16x32_bf16(avh[mf], bl, acc[mf][nf], 0, 0, 0);
      }
    }
    __syncthreads();
  }

  // epilogue: D frag: col = lane&15, row = (lane>>4)*4 + r
  const int r0 = m0 + wr + (lane >> 4) * 4;
  const int c0 = n0 + wc + fm;
  #pragma unroll
  for (int mf = 0; mf < 4; mf++) {
    #pragma unroll
    for (int nf = 0; nf < 4; nf++) {
      const int col = c0 + nf * 16;
      #pragma unroll
      for (int r = 0; r < 4; r++) {
        const int row = r0 + mf * 16 + r;
        const size_t idx = (size_t)row * N + col;
        float v = acc[mf][nf][r];
        float o;
        if constexpr (EPI == 0) {
          o = v;
        } else if constexpr (EPI == 1) {
          const float g = v / (1.f + expf(-v));
          o = g * aux[idx];
        } else if constexpr (EPI == 2) {
          o = v + aux[idx];
        } else if constexpr (EPI == 3) {
          v += bias[col];
          o = 0.5f * v * (1.f + erff(v * 0.70710678118654752f));
        } else if constexpr (EPI == 4) {
          o = v + bias[col] + aux[idx];
        } else {
          v += bias[col];
          o = wave2[0] * sinf(v) + wave2[1] * cosf(v);
        }
        if constexpr (OSPLIT == 0) {
          C[idx] = o;
        } else {
          const unsigned int hb = bfh16(o);
          Ch[idx] = (u16)hb;
          Cl[idx] = (u16)bfh16(o - __uint_as_float(hb << 16));
        }
      }
    }
  }
}

// ---- launch --------------------------------------------------------------

extern "C" void kernel_launch(void* const* d_in, const int* in_sizes, int n_in,
                              void* d_out, int out_size, void* d_ws, size_t ws_size,
                              hipStream_t stream) {
  (void)in_sizes; (void)n_in; (void)out_size;
  const float* x    = (const float*)d_in[0];
  const float* t    = (const float*)d_in[1];
  const float* embW = (const float*)d_in[2];
  const float* embB = (const float*)d_in[3];
  const float* ln1w = (const float*)d_in[4];
  const float* ln1b = (const float*)d_in[5];
  const float* ln2w = (const float*)d_in[6];
  const float* ln2b = (const float*)d_in[7];
  const float* WQ   = (const float*)d_in[8];
  const float* WK   = (const float*)d_in[9];
  const float* WV   = (const float*)d_in[10];
  const float* WG   = (const float*)d_in[11];
  const float* WO   = (const float*)d_in[12];
  const float* gnw  = (const float*)d_in[13];
  const float* gnb  = (const float*)d_in[14];
  const float* f1W  = (const float*)d_in[15];
  const float* f1b  = (const float*)d_in[16];
  const float* f2W  = (const float*)d_in[17];
  const float* f2bp = (const float*)d_in[18];
  const float* h1W  = (const float*)d_in[19];
  const float* h1b  = (const float*)d_in[20];
  const float* wvw  = (const float*)d_in[21];
  const float* h2W  = (const float*)d_in[22];
  const float* h2b  = (const float*)d_in[23];
  const float* h3W  = (const float*)d_in[24];
  const float* h3b  = (const float*)d_in[25];

  // ---- packed-weight area (bf16 hi/lo, [N][K]) at start of ws ----
  u16* P = (u16*)d_ws;
  const size_t SQKV = 2048 * 512, SWG = 1024 * 512, SWO = 512 * 1024;
  const size_t SF1 = 128 * 512, SF2 = 512 * 128;
  const size_t PERL = 2 * (SQKV + SWG + SWO + SF1 + SF2);
  const size_t HOFF = 4 * PERL;                 // heads after layers
  const size_t PACK_BYTES = (HOFF + 4 * 512 * 512) * 2;  // = 37748736

  u16* h1h = P + HOFF;
  u16* h1l = h1h + 512 * 512;
  u16* h2h = h1l + 512 * 512;
  u16* h2l = h2h + 512 * 512;

  const dim3 blk(256);

  // pack all weights once
  for (int l = 0; l < 4; l++) {
    u16* qkvh = P + l * PERL;
    u16* qkvl = qkvh + SQKV;
    u16* wgh  = qkvl + SQKV;
    u16* wgl  = wgh + SWG;
    u16* woh  = wgl + SWG;
    u16* wol  = woh + SWO;
    u16* f1h  = wol + SWO;
    u16* f1l  = f1h + SF1;
    u16* f2h  = f1l + SF1;
    u16* f2l  = f2h + SF2;
    pack_qkv<<<dim3(SQKV / 256), blk, 0, stream>>>(
        WQ + (size_t)l * 262144, WK + (size_t)l * 262144,
        WV + (size_t)l * 524288, qkvh, qkvl);
    pack_plain<<<dim3(SWG / 256), blk, 0, stream>>>(WG + (size_t)l * 524288, wgh, wgl, 1024, 9);
    pack_plain<<<dim3(SWO / 256), blk, 0, stream>>>(WO + (size_t)l * 524288, woh, wol, 512, 10);
    pack_plain<<<dim3(SF1 / 256), blk, 0, stream>>>(f1W + (size_t)l * 65536, f1h, f1l, 128, 9);
    pack_plain<<<dim3(SF2 / 256), blk, 0, stream>>>(f2W + (size_t)l * 65536, f2h, f2l, 512, 7);
  }
  pack_plain<<<dim3(1024), blk, 0, stream>>>(h1W, h1h, h1l, 512, 9);
  pack_plain<<<dim3(1024), blk, 0, stream>>>(h2W, h2h, h2l, 512, 9);

  // ---- batch-chunking so fp32 activations fit after the pack area ----
  int NC = 1;
  while (NC < 256) {
    const size_t R = 65536u / NC;
    if (PACK_BYTES + R * 18432 + 4096 <= ws_size) break;
    NC <<= 1;
  }
  const int R = 65536 / NC;   // rows per chunk (multiple of 256)

  float* Xf   = (float*)((char*)d_ws + PACK_BYTES);  // R x 512 residual
  float* Xn   = Xf  + (size_t)R * 512;   // R x 512   slot: LN split planes / H1 fp32
  float* QKVb = Xn  + (size_t)R * 512;   // R x 2048  QKV fp32; later GY planes
  float* Yb   = QKVb + (size_t)R * 2048; // R x 1024  Y fp32 / mid planes / H2 fp32
  float* Yr   = Yb  + (size_t)R * 1024;  // R x 512   Yr residual branch

  // plane aliases (same footprint as the fp32 slots they replace)
  u16* Xnh = (u16*)Xn;           u16* Xnl = Xnh + (size_t)R * 512;
  u16* GYh = (u16*)QKVb;         u16* GYl = GYh + (size_t)R * 1024;
  u16* midh = (u16*)Yb;          u16* midl = midh + (size_t)R * 128;

  for (int c = 0; c < NC; c++) {
    const size_t off = (size_t)c * R;
    embed_kernel<<<dim3(R / 4), blk, 0, stream>>>(x + off, t + off, embW, embB, Xf);

    for (int l = 0; l < 4; l++) {
      u16* qkvh = P + l * PERL;
      u16* qkvl = qkvh + SQKV;
      u16* wgh  = qkvl + SQKV;
      u16* wgl  = wgh + SWG;
      u16* woh  = wgl + SWG;
      u16* wol  = woh + SWO;
      u16* f1h  = wol + SWO;
      u16* f1l  = f1h + SF1;
      u16* f2h  = f1l + SF1;
      u16* f2l  = f2h + SF2;

      ln_split<<<dim3(R / 4), blk, 0, stream>>>(Xf, ln1w + l * 512, ln1b + l * 512, Xnh, Xnl);
      // QKV = Xn @ [WQ|WK|WV][l]  (fp32 out, raw — rotation happens in attn)
      gemm_mfma<0, 1, 0><<<dim3(16, R / 128), blk, 0, stream>>>(
          nullptr, Xnh, Xnl, qkvh, qkvl, QKVb, nullptr, nullptr,
          2048, 512, nullptr, nullptr, nullptr);
      // fused xpos + causal retention + groupnorm
      attn_fused<<<dim3(R / 64, 8), blk, 0, stream>>>(
          QKVb, Yb, gnw + l * 1024, gnb + l * 1024);
      // GY = silu(Xn @ WG[l]) * Y  -> split planes in QKVb (QKV dead)
      gemm_mfma<1, 1, 1><<<dim3(8, R / 128), blk, 0, stream>>>(
          nullptr, Xnh, Xnl, wgh, wgl, nullptr, GYh, GYl,
          1024, 512, nullptr, Yb, nullptr);
      // Yr = GY @ WO[l] + X
      gemm_mfma<2, 1, 0><<<dim3(4, R / 128), blk, 0, stream>>>(
          nullptr, GYh, GYl, woh, wol, Yr, nullptr, nullptr,
          512, 1024, nullptr, Xf, nullptr);
      ln_split<<<dim3(R / 4), blk, 0, stream>>>(Yr, ln2w + l * 512, ln2b + l * 512, Xnh, Xnl);
      // mid = gelu(Xn @ f1[l] + b1)  -> split planes in Yb
      gemm_mfma<3, 1, 1><<<dim3(1, R / 128), blk, 0, stream>>>(
          nullptr, Xnh, Xnl, f1h, f1l, nullptr, midh, midl,
          128, 512, f1b + l * 128, nullptr, nullptr);
      // X = mid @ f2[l] + b2 + Yr
      gemm_mfma<4, 1, 0><<<dim3(4, R / 128), blk, 0, stream>>>(
          nullptr, midh, midl, f2h, f2l, Xf, nullptr, nullptr,
          512, 128, f2bp + l * 512, Yr, nullptr);
    }

    // head (A operands are fp32 here; AMODE0 splits in-kernel)
    gemm_mfma<5, 0, 0><<<dim3(4, R / 128), blk, 0, stream>>>(
        Xf, nullptr, nullptr, h1h, h1l, Xn, nullptr, nullptr,
        512, 512, h1b, nullptr, wvw);
    gemm_mfma<5, 0, 0><<<dim3(4, R / 128), blk, 0, stream>>>(
        Xn, nullptr, nullptr, h2h, h2l, Yb, nullptr, nullptr,
        512, 512, h2b, nullptr, wvw + 2);
    head3_kernel<<<dim3(R / 4), blk, 0, stream>>>(
        Yb, h3W, h3b, (float*)d_out + off);
  }
}

// Round 4
// 12581.084 us; speedup vs baseline: 1.7054x; 1.7054x over previous
//
#include <hip/hip_runtime.h>
#include <cstdint>
#include <cstddef>

#define DEV static __device__ __forceinline__

typedef short bf16x8 __attribute__((ext_vector_type(8)));
typedef float f32x4 __attribute__((ext_vector_type(4)));
typedef unsigned short u16;

DEV float wredf(float v) {
  v += __shfl_xor(v, 32, 64); v += __shfl_xor(v, 16, 64);
  v += __shfl_xor(v, 8, 64);  v += __shfl_xor(v, 4, 64);
  v += __shfl_xor(v, 2, 64);  v += __shfl_xor(v, 1, 64);
  return v;
}

DEV void ld4(float* d, const float* p) {
  float4 t = *(const float4*)p;
  d[0] = t.x; d[1] = t.y; d[2] = t.z; d[3] = t.w;
}
DEV void st4(float* p, const float* s) {
  *(float4*)p = make_float4(s[0], s[1], s[2], s[3]);
}

// round-to-nearest-even fp32 -> bf16 bits
DEV unsigned int bfh16(float v) {
  unsigned int u = __float_as_uint(v);
  return (u + 0x7FFFu + ((u >> 16) & 1u)) >> 16;
}
// split pair (a,b) -> packed hi-word / lo-word (2x bf16 each)
DEV uint2 splitpk(float a, float b) {
  unsigned int ha = bfh16(a), hb = bfh16(b);
  float la = a - __uint_as_float(ha << 16);
  float lb = b - __uint_as_float(hb << 16);
  return make_uint2(ha | (hb << 16), bfh16(la) | (bfh16(lb) << 16));
}

// async global->LDS, 16B per lane: LDS dest = base + lane*16 (HW), global
// src is per-lane.
DEV void gload_lds16(const void* g, void* l) {
  __builtin_amdgcn_global_load_lds(
      (const __attribute__((address_space(1))) unsigned int*)g,
      (__attribute__((address_space(3))) unsigned int*)l, 16, 0, 0);
}

// ---- embed: src = [x,t] @ emb_W + emb_b  (fp32) --------------------------
__global__ __launch_bounds__(256)
void embed_kernel(const float* __restrict__ x, const float* __restrict__ t,
                  const float* __restrict__ W, const float* __restrict__ eb,
                  float* __restrict__ X) {
  const int gid = blockIdx.x * 256 + threadIdx.x;  // R*64
  const int row = gid >> 6, d = (gid & 63) * 8;
  const float xv = x[row], tv = t[row];
  #pragma unroll
  for (int j = 0; j < 8; j++)
    X[(size_t)row * 512 + d + j] =
        xv * W[d + j] + tv * W[512 + d + j] + eb[d + j];
}

// ---- layernorm row=512, fp32 -> split bf16 hi/lo planes ------------------
__global__ __launch_bounds__(256)
void ln_split(const float* __restrict__ X, const float* __restrict__ w,
              const float* __restrict__ bb, u16* __restrict__ hi,
              u16* __restrict__ lo) {
  const int row = blockIdx.x * 4 + (threadIdx.x >> 6);
  const int lane = threadIdx.x & 63;
  const float* xp = X + (size_t)row * 512 + lane * 8;
  float4 a0 = *(const float4*)xp;
  float4 a1 = *(const float4*)(xp + 4);
  float v[8] = {a0.x, a0.y, a0.z, a0.w, a1.x, a1.y, a1.z, a1.w};
  float s = 0.f, sq = 0.f;
  #pragma unroll
  for (int j = 0; j < 8; j++) { s += v[j]; sq += v[j] * v[j]; }
  s = wredf(s); sq = wredf(sq);
  const float mean = s * (1.f / 512.f);
  const float var = fmaxf(sq * (1.f / 512.f) - mean * mean, 0.f);
  const float inv = rsqrtf(var + 1e-5f);
  const float* wp = w + lane * 8;
  const float* bp = bb + lane * 8;
  float o[8];
  #pragma unroll
  for (int j = 0; j < 8; j++)
    o[j] = (v[j] - mean) * inv * wp[j] + bp[j];
  uint2 p0 = splitpk(o[0], o[1]), p1 = splitpk(o[2], o[3]);
  uint2 p2 = splitpk(o[4], o[5]), p3 = splitpk(o[6], o[7]);
  const size_t off = (size_t)row * 512 + lane * 8;
  *(int4*)(hi + off) = make_int4(p0.x, p1.x, p2.x, p3.x);
  *(int4*)(lo + off) = make_int4(p0.y, p1.y, p2.y, p3.y);
}

// ---- xpos rotation + folded retention decay on Q,K (one pass) ------------
__global__ __launch_bounds__(256)
void xpos_kernel(float* __restrict__ QKV) {
  const int gid = blockIdx.x * 256 + threadIdx.x;  // R*256
  const int row = gid >> 8, r = gid & 255;
  const int h = r >> 5, i = r & 31;
  const int s = row & 255;
  const float sv = (2.0f * i + 0.4f * 64.0f) / (1.4f * 64.0f);
  const float sc = powf(sv, (float)s / 512.0f);
  const float isc = 1.0f / sc;
  const float invf = powf(10000.0f, -((float)i) / 32.0f);
  const float ang = (float)s * invf;
  const float sn = sinf(ang), cs = cosf(ang);
  const float l32 = logf(1.0f / 32.0f), l512 = logf(1.0f / 512.0f);
  const float gamma = 1.0f - expf(l32 + (float)h * (l512 - l32) / 7.0f);
  const float gq = powf(gamma, (float)s);
  const float gk = 1.0f / gq;
  const size_t base = (size_t)row * 2048 + h * 64 + 2 * i;
  const float q0 = QKV[base], q1 = QKV[base + 1];
  const float k0 = QKV[base + 512], k1 = QKV[base + 513];
  const float cq = cs * sc * gq, sq_ = sn * sc * gq;
  const float ck = cs * isc * gk, sk = sn * isc * gk;
  QKV[base]       = q0 * cq - q1 * sq_;
  QKV[base + 1]   = q1 * cq + q0 * sq_;
  QKV[base + 512] = k0 * ck - k1 * sk;
  QKV[base + 513] = k1 * ck + k0 * sk;
}

// ---- tiled causal retention attention (fp32, decay pre-folded) -----------
__global__ __launch_bounds__(256)
void attn_tiled(const float* __restrict__ QKV, float* __restrict__ Y) {
  __shared__ float Qs[64][68];   // [e][s]
  __shared__ float Ks[64][68];   // [e][m]
  __shared__ float At[64][68];   // [m][s]
  const int h = blockIdx.y;
  const int r0 = blockIdx.x * 64;       // chunk-local first row
  const int b = r0 >> 8;
  const int s0 = r0 & 255;
  const int st = s0 >> 6;               // diagonal m-tile index
  const int tid = threadIdx.x;
  const int ty = tid >> 4, tx = tid & 15;

  {  // stage Q transposed
    const int rr = tid >> 2, e0 = (tid & 3) * 16;
    const float* qp = QKV + (size_t)(r0 + rr) * 2048 + h * 64 + e0;
    #pragma unroll
    for (int j = 0; j < 16; j++) Qs[e0 + j][rr] = qp[j];
  }

  float acc2[4][8];
  #pragma unroll
  for (int i = 0; i < 4; i++)
    #pragma unroll
    for (int j = 0; j < 8; j++) acc2[i][j] = 0.f;

  for (int mt = 0; mt <= st; mt++) {
    const int m0 = mt * 64;
    {  // stage K tile transposed
      const int rr = tid >> 2, e0 = (tid & 3) * 16;
      const float* kp = QKV + (size_t)(b * 256 + m0 + rr) * 2048 + 512 + h * 64 + e0;
      #pragma unroll
      for (int j = 0; j < 16; j++) Ks[e0 + j][rr] = kp[j];
    }
    __syncthreads();
    float a1[4][4];
    #pragma unroll
    for (int i = 0; i < 4; i++)
      #pragma unroll
      for (int j = 0; j < 4; j++) a1[i][j] = 0.f;
    #pragma unroll 4
    for (int e = 0; e < 64; e++) {
      float qa[4], kb[4];
      ld4(qa, &Qs[e][ty * 4]);
      ld4(kb, &Ks[e][tx * 4]);
      #pragma unroll
      for (int i = 0; i < 4; i++)
        #pragma unroll
        for (int j = 0; j < 4; j++)
          a1[i][j] = fmaf(qa[i], kb[j], a1[i][j]);
    }
    #pragma unroll
    for (int i = 0; i < 4; i++)
      #pragma unroll
      for (int j = 0; j < 4; j++) {
        float v = a1[i][j];
        if (mt == st && (m0 + tx * 4 + j) > (s0 + ty * 4 + i)) v = 0.f;
        At[tx * 4 + j][ty * 4 + i] = v;
      }
    __syncthreads();
    const float* vp = QKV + (size_t)(b * 256 + m0) * 2048 + 1024 + h * 128 + tx * 8;
    #pragma unroll 4
    for (int m = 0; m < 64; m++) {
      float av[4], vv[8];
      ld4(av, &At[m][ty * 4]);
      ld4(vv, vp);
      ld4(vv + 4, vp + 4);
      vp += 2048;
      #pragma unroll
      for (int i = 0; i < 4; i++)
        #pragma unroll
        for (int j = 0; j < 8; j++)
          acc2[i][j] = fmaf(av[i], vv[j], acc2[i][j]);
    }
    __syncthreads();
  }
  #pragma unroll
  for (int i = 0; i < 4; i++) {
    float* yp = Y + (size_t)(r0 + ty * 4 + i) * 1024 + h * 128 + tx * 8;
    st4(yp, &acc2[i][0]);
    st4(yp + 4, &acc2[i][4]);
  }
}

// ---- group norm over 128 per (row,h), in place + affine ------------------
__global__ __launch_bounds__(256)
void gn_kernel(float* __restrict__ Y, const float* __restrict__ w,
               const float* __restrict__ bb) {
  const int wave = threadIdx.x >> 6, lane = threadIdx.x & 63;
  #pragma unroll
  for (int rep = 0; rep < 4; rep++) {
    const int grp = blockIdx.x * 16 + wave * 4 + rep;   // srow*8 + h
    const int h = grp & 7;
    float* yp = Y + (size_t)grp * 128 + lane * 2;
    const float y0 = yp[0], y1 = yp[1];
    const float s = wredf(y0 + y1);
    const float sq = wredf(y0 * y0 + y1 * y1);
    const float mean = s * (1.f / 128.f);
    const float var = fmaxf(sq * (1.f / 128.f) - mean * mean, 0.f);
    const float inv = rsqrtf(var + 1e-5f);
    const int vi = h * 128 + lane * 2;
    yp[0] = (y0 - mean) * inv * w[vi] + bb[vi];
    yp[1] = (y1 - mean) * inv * w[vi + 1] + bb[vi + 1];
  }
}

// ---- final N=1 dot (fp32) ------------------------------------------------
__global__ __launch_bounds__(256)
void head3_kernel(const float* __restrict__ X, const float* __restrict__ w,
                  const float* __restrict__ b3, float* __restrict__ out) {
  const int row = blockIdx.x * 4 + (threadIdx.x >> 6);
  const int lane = threadIdx.x & 63;
  const float* xp = X + (size_t)row * 512 + lane * 8;
  const float* wp = w + lane * 8;
  float s = 0.f;
  #pragma unroll
  for (int j = 0; j < 8; j++) s += xp[j] * wp[j];
  s = wredf(s);
  if (lane == 0) out[row] = s + b3[0];
}

// ---- weight pre-pack: W[K][N] (fp32) -> Bt_hi/Bt_lo [N][K] (bf16) --------
__global__ __launch_bounds__(256)
void pack_plain(const float* __restrict__ W, u16* __restrict__ hi,
                u16* __restrict__ lo, int N, int kshift) {
  const int idx = blockIdx.x * 256 + threadIdx.x;   // n*K + k
  const int K = 1 << kshift;
  const int n = idx >> kshift, k = idx & (K - 1);
  const float v = W[(size_t)k * N + n];
  const unsigned int h = bfh16(v);
  const float l = v - __uint_as_float(h << 16);
  hi[idx] = (u16)h;
  lo[idx] = (u16)bfh16(l);
}

// QKV head-interleaved mapping: col c<512 -> WQ(h,k,e), <1024 -> WK, else WV
__global__ __launch_bounds__(256)
void pack_qkv(const float* __restrict__ WQ, const float* __restrict__ WK,
              const float* __restrict__ WV, u16* __restrict__ hi,
              u16* __restrict__ lo) {
  const int idx = blockIdx.x * 256 + threadIdx.x;   // c*512 + k
  const int c = idx >> 9, k = idx & 511;
  float v;
  if (c < 512)
    v = WQ[((size_t)(c >> 6) * 512 + k) * 64 + (c & 63)];
  else if (c < 1024)
    v = WK[((size_t)((c - 512) >> 6) * 512 + k) * 64 + ((c - 512) & 63)];
  else
    v = WV[((size_t)((c - 1024) >> 7) * 512 + k) * 128 + ((c - 1024) & 127)];
  const unsigned int h = bfh16(v);
  const float l = v - __uint_as_float(h << 16);
  hi[idx] = (u16)h;
  lo[idx] = (u16)bfh16(l);
}

// ---- bf16x3 MFMA GEMM, global_load_lds staging (m97 structure) -----------
// A pre-split [M][K] hi/lo bf16 planes; B pre-packed [N][K] hi/lo.
// 128x128 tile, BK=32, 4 waves; LDS linear [plane][128][32]; wave w stages
// plane w via 8x global_load_lds_dwordx4 (1KB each). 4x4 frags 16x16x32.
// acc += ah*bh + ah*bl + al*bh.
// EPI 0: store    1: silu(acc)*aux     2: acc+aux
//     3: gelu(acc+bias)   4: acc+bias+aux   5: w0*sin(acc+b)+w1*cos(acc+b)
// OSPLIT 0: fp32 C.  1: split bf16 hi/lo planes Ch/Cl.
template<int EPI, int OSPLIT>
__global__ __launch_bounds__(256, 2)
void gemm_lds(const u16* __restrict__ Agh, const u16* __restrict__ Agl,
              const u16* __restrict__ Bh, const u16* __restrict__ Bl,
              float* __restrict__ C, u16* __restrict__ Ch, u16* __restrict__ Cl,
              const int N, const int K,
              const float* __restrict__ bias, const float* __restrict__ aux,
              const float* __restrict__ wave2) {
  __shared__ __align__(16) u16 S[4][128][32];   // Ah, Al, Bh, Bl
  const int tid = threadIdx.x;
  const int lane = tid & 63;
  const int wave = tid >> 6;
  const int wr = (wave >> 1) * 64, wc = (wave & 1) * 64;
  const int m0 = blockIdx.y * 128, n0 = blockIdx.x * 128;

  const int fm = lane & 15;
  const int fke = (lane >> 4) * 8;    // element offset of lane's k-slice

  // staging: wave w owns plane w; issue i covers rows [i*16, i*16+16).
  // lane -> (row = i*16 + lane/4, elems (lane&3)*8): LDS off = lane*16B.
  const u16* pb;
  if (wave == 0)      pb = Agh + (size_t)m0 * K;
  else if (wave == 1) pb = Agl + (size_t)m0 * K;
  else if (wave == 2) pb = Bh + (size_t)n0 * K;
  else                pb = Bl + (size_t)n0 * K;
  const u16* src0 = pb + (size_t)(lane >> 2) * K + (lane & 3) * 8;
  u16* dst0 = &S[wave][0][0];

  f32x4 acc[4][4];
  #pragma unroll
  for (int i = 0; i < 4; i++)
    #pragma unroll
    for (int j = 0; j < 4; j++)
      acc[i][j] = (f32x4){0.f, 0.f, 0.f, 0.f};

  for (int kt = 0; kt < K; kt += 32) {
    #pragma unroll
    for (int i = 0; i < 8; i++)
      gload_lds16(src0 + (size_t)(i * 16) * K + kt, dst0 + i * 512);
    __syncthreads();    // compiler drains vmcnt before barrier

    bf16x8 avh[4], avl[4];
    #pragma unroll
    for (int mf = 0; mf < 4; mf++) {
      const int m = wr + mf * 16 + fm;
      avh[mf] = *(const bf16x8*)&S[0][m][fke];
      avl[mf] = *(const bf16x8*)&S[1][m][fke];
    }
    #pragma unroll
    for (int nf = 0; nf < 4; nf++) {
      const int n = wc + nf * 16 + fm;
      bf16x8 bh = *(const bf16x8*)&S[2][n][fke];
      bf16x8 bl = *(const bf16x8*)&S[3][n][fke];
      #pragma unroll
      for (int mf = 0; mf < 4; mf++) {
        acc[mf][nf] = __builtin_amdgcn_mfma_f32_16x16x32_bf16(avh[mf], bh, acc[mf][nf], 0, 0, 0);
        acc[mf][nf] = __builtin_amdgcn_mfma_f32_16x16x32_bf16(avl[mf], bh, acc[mf][nf], 0, 0, 0);
        acc[mf][nf] = __builtin_amdgcn_mfma_f32_16x16x32_bf16(avh[mf], bl, acc[mf][nf], 0, 0, 0);
      }
    }
    __syncthreads();
  }

  // epilogue: D frag: col = lane&15, row = (lane>>4)*4 + r
  const int r0 = m0 + wr + (lane >> 4) * 4;
  const int c0 = n0 + wc + fm;
  #pragma unroll
  for (int mf = 0; mf < 4; mf++) {
    #pragma unroll
    for (int nf = 0; nf < 4; nf++) {
      const int col = c0 + nf * 16;
      #pragma unroll
      for (int r = 0; r < 4; r++) {
        const int row = r0 + mf * 16 + r;
        const size_t idx = (size_t)row * N + col;
        float v = acc[mf][nf][r];
        float o;
        if constexpr (EPI == 0) {
          o = v;
        } else if constexpr (EPI == 1) {
          const float g = v / (1.f + expf(-v));
          o = g * aux[idx];
        } else if constexpr (EPI == 2) {
          o = v + aux[idx];
        } else if constexpr (EPI == 3) {
          v += bias[col];
          o = 0.5f * v * (1.f + erff(v * 0.70710678118654752f));
        } else if constexpr (EPI == 4) {
          o = v + bias[col] + aux[idx];
        } else {
          v += bias[col];
          o = wave2[0] * sinf(v) + wave2[1] * cosf(v);
        }
        if constexpr (OSPLIT == 0) {
          C[idx] = o;
        } else {
          const unsigned int hb = bfh16(o);
          Ch[idx] = (u16)hb;
          Cl[idx] = (u16)bfh16(o - __uint_as_float(hb << 16));
        }
      }
    }
  }
}

// ---- reg-staged bf16x3 GEMM for fp32-A inputs (heads only) ---------------
template<int EPI>
__global__ __launch_bounds__(256, 2)
void gemm_mfma(const float* __restrict__ Af, const u16* __restrict__ Bh,
               const u16* __restrict__ Bl, float* __restrict__ C,
               const int N, const int K,
               const float* __restrict__ bias, const float* __restrict__ aux,
               const float* __restrict__ wave2) {
  __shared__ __align__(16) u16 Ah[128][40];
  __shared__ __align__(16) u16 Al[128][40];
  __shared__ __align__(16) u16 Bhs[128][40];
  __shared__ __align__(16) u16 Bls[128][40];
  const int tid = threadIdx.x;
  const int lane = tid & 63;
  const int wave = tid >> 6;
  const int wr = (wave >> 1) * 64, wc = (wave & 1) * 64;
  const int m0 = blockIdx.y * 128, n0 = blockIdx.x * 128;

  const int ar = tid >> 1;
  const int aks = (tid & 1) * 16;
  const int bu = tid & 127;
  const u16* Bp = ((tid >> 7) ? Bl : Bh) + (size_t)(n0 + bu) * K;
  u16* Bw = ((tid >> 7) ? &Bls[0][0] : &Bhs[0][0]) + bu * 40;

  const int fm = lane & 15;
  const int fkb = (lane >> 4) * 16;

  f32x4 acc[4][4];
  #pragma unroll
  for (int i = 0; i < 4; i++)
    #pragma unroll
    for (int j = 0; j < 4; j++)
      acc[i][j] = (f32x4){0.f, 0.f, 0.f, 0.f};

  const float* Ap = Af + (size_t)(m0 + ar) * K + aks;
  float a_reg[16];
  int4 b_reg[4];
  ld4(a_reg, Ap);        ld4(a_reg + 4, Ap + 4);
  ld4(a_reg + 8, Ap + 8); ld4(a_reg + 12, Ap + 12);
  #pragma unroll
  for (int i = 0; i < 4; i++) b_reg[i] = *(const int4*)(Bp + i * 8);

  for (int kt = 0; kt < K; kt += 32) {
    {
      uint2 q0 = splitpk(a_reg[0], a_reg[1]);
      uint2 q1 = splitpk(a_reg[2], a_reg[3]);
      uint2 q2 = splitpk(a_reg[4], a_reg[5]);
      uint2 q3 = splitpk(a_reg[6], a_reg[7]);
      uint2 q4 = splitpk(a_reg[8], a_reg[9]);
      uint2 q5 = splitpk(a_reg[10], a_reg[11]);
      uint2 q6 = splitpk(a_reg[12], a_reg[13]);
      uint2 q7 = splitpk(a_reg[14], a_reg[15]);
      *(int4*)&Ah[ar][aks]     = make_int4(q0.x, q1.x, q2.x, q3.x);
      *(int4*)&Ah[ar][aks + 8] = make_int4(q4.x, q5.x, q6.x, q7.x);
      *(int4*)&Al[ar][aks]     = make_int4(q0.y, q1.y, q2.y, q3.y);
      *(int4*)&Al[ar][aks + 8] = make_int4(q4.y, q5.y, q6.y, q7.y);
      *(int4*)&Bw[0]  = b_reg[0];
      *(int4*)&Bw[8]  = b_reg[1];
      *(int4*)&Bw[16] = b_reg[2];
      *(int4*)&Bw[24] = b_reg[3];
    }
    __syncthreads();
    if (kt + 32 < K) {
      const float* ap = Ap + kt + 32;
      ld4(a_reg, ap);        ld4(a_reg + 4, ap + 4);
      ld4(a_reg + 8, ap + 8); ld4(a_reg + 12, ap + 12);
      const u16* bp = Bp + kt + 32;
      #pragma unroll
      for (int i = 0; i < 4; i++) b_reg[i] = *(const int4*)(bp + i * 8);
    }
    bf16x8 avh[4], avl[4];
    #pragma unroll
    for (int mf = 0; mf < 4; mf++) {
      const int m = wr + mf * 16 + fm;
      avh[mf] = *(const bf16x8*)((const char*)&Ah[m][0] + fkb);
      avl[mf] = *(const bf16x8*)((const char*)&Al[m][0] + fkb);
    }
    #pragma unroll
    for (int nf = 0; nf < 4; nf++) {
      const int n = wc + nf * 16 + fm;
      bf16x8 bh = *(const bf16x8*)((const char*)&Bhs[n][0] + fkb);
      bf16x8 bl = *(const bf16x8*)((const char*)&Bls[n][0] + fkb);
      #pragma unroll
      for (int mf = 0; mf < 4; mf++) {
        acc[mf][nf] = __builtin_amdgcn_mfma_f32_16x16x32_bf16(avh[mf], bh, acc[mf][nf], 0, 0, 0);
        acc[mf][nf] = __builtin_amdgcn_mfma_f32_16x16x32_bf16(avl[mf], bh, acc[mf][nf], 0, 0, 0);
        acc[mf][nf] = __builtin_amdgcn_mfma_f32_16x16x32_bf16(avh[mf], bl, acc[mf][nf], 0, 0, 0);
      }
    }
    __syncthreads();
  }

  const int r0 = m0 + wr + (lane >> 4) * 4;
  const int c0 = n0 + wc + fm;
  #pragma unroll
  for (int mf = 0; mf < 4; mf++) {
    #pragma unroll
    for (int nf = 0; nf < 4; nf++) {
      const int col = c0 + nf * 16;
      #pragma unroll
      for (int r = 0; r < 4; r++) {
        const int row = r0 + mf * 16 + r;
        const size_t idx = (size_t)row * N + col;
        float v = acc[mf][nf][r];
        float o;
        if constexpr (EPI == 5) {
          v += bias[col];
          o = wave2[0] * sinf(v) + wave2[1] * cosf(v);
        } else {
          o = v;
        }
        C[idx] = o;
      }
    }
  }
}

// ---- launch --------------------------------------------------------------

extern "C" void kernel_launch(void* const* d_in, const int* in_sizes, int n_in,
                              void* d_out, int out_size, void* d_ws, size_t ws_size,
                              hipStream_t stream) {
  (void)in_sizes; (void)n_in; (void)out_size;
  const float* x    = (const float*)d_in[0];
  const float* t    = (const float*)d_in[1];
  const float* embW = (const float*)d_in[2];
  const float* embB = (const float*)d_in[3];
  const float* ln1w = (const float*)d_in[4];
  const float* ln1b = (const float*)d_in[5];
  const float* ln2w = (const float*)d_in[6];
  const float* ln2b = (const float*)d_in[7];
  const float* WQ   = (const float*)d_in[8];
  const float* WK   = (const float*)d_in[9];
  const float* WV   = (const float*)d_in[10];
  const float* WG   = (const float*)d_in[11];
  const float* WO   = (const float*)d_in[12];
  const float* gnw  = (const float*)d_in[13];
  const float* gnb  = (const float*)d_in[14];
  const float* f1W  = (const float*)d_in[15];
  const float* f1b  = (const float*)d_in[16];
  const float* f2W  = (const float*)d_in[17];
  const float* f2bp = (const float*)d_in[18];
  const float* h1W  = (const float*)d_in[19];
  const float* h1b  = (const float*)d_in[20];
  const float* wvw  = (const float*)d_in[21];
  const float* h2W  = (const float*)d_in[22];
  const float* h2b  = (const float*)d_in[23];
  const float* h3W  = (const float*)d_in[24];
  const float* h3b  = (const float*)d_in[25];

  // ---- packed-weight area (bf16 hi/lo, [N][K]) at start of ws ----
  u16* P = (u16*)d_ws;
  const size_t SQKV = 2048 * 512, SWG = 1024 * 512, SWO = 512 * 1024;
  const size_t SF1 = 128 * 512, SF2 = 512 * 128;
  const size_t PERL = 2 * (SQKV + SWG + SWO + SF1 + SF2);
  const size_t HOFF = 4 * PERL;                 // heads after layers
  const size_t PACK_BYTES = (HOFF + 4 * 512 * 512) * 2;  // = 37748736

  u16* h1h = P + HOFF;
  u16* h1l = h1h + 512 * 512;
  u16* h2h = h1l + 512 * 512;
  u16* h2l = h2h + 512 * 512;

  const dim3 blk(256);

  // pack all weights once
  for (int l = 0; l < 4; l++) {
    u16* qkvh = P + l * PERL;
    u16* qkvl = qkvh + SQKV;
    u16* wgh  = qkvl + SQKV;
    u16* wgl  = wgh + SWG;
    u16* woh  = wgl + SWG;
    u16* wol  = woh + SWO;
    u16* f1h  = wol + SWO;
    u16* f1l  = f1h + SF1;
    u16* f2h  = f1l + SF1;
    u16* f2l  = f2h + SF2;
    pack_qkv<<<dim3(SQKV / 256), blk, 0, stream>>>(
        WQ + (size_t)l * 262144, WK + (size_t)l * 262144,
        WV + (size_t)l * 524288, qkvh, qkvl);
    pack_plain<<<dim3(SWG / 256), blk, 0, stream>>>(WG + (size_t)l * 524288, wgh, wgl, 1024, 9);
    pack_plain<<<dim3(SWO / 256), blk, 0, stream>>>(WO + (size_t)l * 524288, woh, wol, 512, 10);
    pack_plain<<<dim3(SF1 / 256), blk, 0, stream>>>(f1W + (size_t)l * 65536, f1h, f1l, 128, 9);
    pack_plain<<<dim3(SF2 / 256), blk, 0, stream>>>(f2W + (size_t)l * 65536, f2h, f2l, 512, 7);
  }
  pack_plain<<<dim3(1024), blk, 0, stream>>>(h1W, h1h, h1l, 512, 9);
  pack_plain<<<dim3(1024), blk, 0, stream>>>(h2W, h2h, h2l, 512, 9);

  // ---- batch-chunking so fp32 activations fit after the pack area ----
  int NC = 1;
  while (NC < 256) {
    const size_t R = 65536u / NC;
    if (PACK_BYTES + R * 18432 + 4096 <= ws_size) break;
    NC <<= 1;
  }
  const int R = 65536 / NC;   // rows per chunk (multiple of 256)

  float* Xf   = (float*)((char*)d_ws + PACK_BYTES);  // R x 512 residual
  float* Xn   = Xf  + (size_t)R * 512;   // R x 512   slot: LN planes / H1 fp32
  float* QKVb = Xn  + (size_t)R * 512;   // R x 2048  QKV fp32; later GY planes
  float* Yb   = QKVb + (size_t)R * 2048; // R x 1024  Y fp32 / mid planes / H2
  float* Yr   = Yb  + (size_t)R * 1024;  // R x 512   Yr residual branch

  u16* Xnh = (u16*)Xn;           u16* Xnl = Xnh + (size_t)R * 512;
  u16* GYh = (u16*)QKVb;         u16* GYl = GYh + (size_t)R * 1024;
  u16* midh = (u16*)Yb;          u16* midl = midh + (size_t)R * 128;

  for (int c = 0; c < NC; c++) {
    const size_t off = (size_t)c * R;
    embed_kernel<<<dim3(R / 4), blk, 0, stream>>>(x + off, t + off, embW, embB, Xf);

    for (int l = 0; l < 4; l++) {
      u16* qkvh = P + l * PERL;
      u16* qkvl = qkvh + SQKV;
      u16* wgh  = qkvl + SQKV;
      u16* wgl  = wgh + SWG;
      u16* woh  = wgl + SWG;
      u16* wol  = woh + SWO;
      u16* f1h  = wol + SWO;
      u16* f1l  = f1h + SF1;
      u16* f2h  = f1l + SF1;
      u16* f2l  = f2h + SF2;

      ln_split<<<dim3(R / 4), blk, 0, stream>>>(Xf, ln1w + l * 512, ln1b + l * 512, Xnh, Xnl);
      // QKV = Xn @ [WQ|WK|WV][l]  (fp32 out)
      gemm_lds<0, 0><<<dim3(16, R / 128), blk, 0, stream>>>(
          Xnh, Xnl, qkvh, qkvl, QKVb, nullptr, nullptr,
          2048, 512, nullptr, nullptr, nullptr);
      xpos_kernel<<<dim3(R), blk, 0, stream>>>(QKVb);
      attn_tiled<<<dim3(R / 64, 8), blk, 0, stream>>>(QKVb, Yb);
      gn_kernel<<<dim3(R / 2), blk, 0, stream>>>(Yb, gnw + l * 1024, gnb + l * 1024);
      // GY = silu(Xn @ WG[l]) * Y  -> split planes in QKVb (QKV dead)
      gemm_lds<1, 1><<<dim3(8, R / 128), blk, 0, stream>>>(
          Xnh, Xnl, wgh, wgl, nullptr, GYh, GYl,
          1024, 512, nullptr, Yb, nullptr);
      // Yr = GY @ WO[l] + X
      gemm_lds<2, 0><<<dim3(4, R / 128), blk, 0, stream>>>(
          GYh, GYl, woh, wol, Yr, nullptr, nullptr,
          512, 1024, nullptr, Xf, nullptr);
      ln_split<<<dim3(R / 4), blk, 0, stream>>>(Yr, ln2w + l * 512, ln2b + l * 512, Xnh, Xnl);
      // mid = gelu(Xn @ f1[l] + b1)  -> split planes in Yb
      gemm_lds<3, 1><<<dim3(1, R / 128), blk, 0, stream>>>(
          Xnh, Xnl, f1h, f1l, nullptr, midh, midl,
          128, 512, f1b + l * 128, nullptr, nullptr);
      // X = mid @ f2[l] + b2 + Yr
      gemm_lds<4, 0><<<dim3(4, R / 128), blk, 0, stream>>>(
          midh, midl, f2h, f2l, Xf, nullptr, nullptr,
          512, 128, f2bp + l * 512, Yr, nullptr);
    }

    // head (A operands fp32; reg-staged kernel splits in-kernel)
    gemm_mfma<5><<<dim3(4, R / 128), blk, 0, stream>>>(
        Xf, h1h, h1l, Xn, 512, 512, h1b, nullptr, wvw);
    gemm_mfma<5><<<dim3(4, R / 128), blk, 0, stream>>>(
        Xn, h2h, h2l, Yb, 512, 512, h2b, nullptr, wvw + 2);
    head3_kernel<<<dim3(R / 4), blk, 0, stream>>>(
        Yb, h3W, h3b, (float*)d_out + off);
  }
}

// Round 5
// 11957.111 us; speedup vs baseline: 1.7944x; 1.0522x over previous
//
#include <hip/hip_runtime.h>
#include <cstdint>
#include <cstddef>

#define DEV static __device__ __forceinline__

typedef short bf16x8 __attribute__((ext_vector_type(8)));
typedef float f32x4 __attribute__((ext_vector_type(4)));
typedef unsigned short u16;

DEV float wredf(float v) {
  v += __shfl_xor(v, 32, 64); v += __shfl_xor(v, 16, 64);
  v += __shfl_xor(v, 8, 64);  v += __shfl_xor(v, 4, 64);
  v += __shfl_xor(v, 2, 64);  v += __shfl_xor(v, 1, 64);
  return v;
}

DEV void ld4(float* d, const float* p) {
  float4 t = *(const float4*)p;
  d[0] = t.x; d[1] = t.y; d[2] = t.z; d[3] = t.w;
}
DEV void st4(float* p, const float* s) {
  *(float4*)p = make_float4(s[0], s[1], s[2], s[3]);
}

// round-to-nearest-even fp32 -> bf16 bits
DEV unsigned int bfh16(float v) {
  unsigned int u = __float_as_uint(v);
  return (u + 0x7FFFu + ((u >> 16) & 1u)) >> 16;
}
// split pair (a,b) -> packed hi-word / lo-word (2x bf16 each)
DEV uint2 splitpk(float a, float b) {
  unsigned int ha = bfh16(a), hb = bfh16(b);
  float la = a - __uint_as_float(ha << 16);
  float lb = b - __uint_as_float(hb << 16);
  return make_uint2(ha | (hb << 16), bfh16(la) | (bfh16(lb) << 16));
}

// T2 swizzle for plane buffers: within each 32-elem k-segment, 16B chunk
// c -> c ^ ((row>>1)&3).  Writers store swizzled; gemm_lds reads swizzled;
// global_load_lds stages linearly (rule #21: swizzle source + read, not dest).
DEV size_t swz_idx(int row, int col, int ld) {
  return (size_t)row * ld + (col & ~31) +
         ((((col >> 3) & 3) ^ ((row >> 1) & 3)) << 3) + (col & 7);
}

// async global->LDS, 16B per lane: LDS dest = base + lane*16 (HW)
DEV void gload_lds16(const void* g, void* l) {
  __builtin_amdgcn_global_load_lds(
      (const __attribute__((address_space(1))) unsigned int*)g,
      (__attribute__((address_space(3))) unsigned int*)l, 16, 0, 0);
}

// ---- embed: src = [x,t] @ emb_W + emb_b  (fp32) --------------------------
__global__ __launch_bounds__(256)
void embed_kernel(const float* __restrict__ x, const float* __restrict__ t,
                  const float* __restrict__ W, const float* __restrict__ eb,
                  float* __restrict__ X) {
  const int gid = blockIdx.x * 256 + threadIdx.x;  // R*64
  const int row = gid >> 6, d = (gid & 63) * 8;
  const float xv = x[row], tv = t[row];
  #pragma unroll
  for (int j = 0; j < 8; j++)
    X[(size_t)row * 512 + d + j] =
        xv * W[d + j] + tv * W[512 + d + j] + eb[d + j];
}

// ---- layernorm row=512, fp32 -> split bf16 hi/lo planes (swizzled) -------
__global__ __launch_bounds__(256)
void ln_split(const float* __restrict__ X, const float* __restrict__ w,
              const float* __restrict__ bb, u16* __restrict__ hi,
              u16* __restrict__ lo) {
  const int row = blockIdx.x * 4 + (threadIdx.x >> 6);
  const int lane = threadIdx.x & 63;
  const float* xp = X + (size_t)row * 512 + lane * 8;
  float4 a0 = *(const float4*)xp;
  float4 a1 = *(const float4*)(xp + 4);
  float v[8] = {a0.x, a0.y, a0.z, a0.w, a1.x, a1.y, a1.z, a1.w};
  float s = 0.f, sq = 0.f;
  #pragma unroll
  for (int j = 0; j < 8; j++) { s += v[j]; sq += v[j] * v[j]; }
  s = wredf(s); sq = wredf(sq);
  const float mean = s * (1.f / 512.f);
  const float var = fmaxf(sq * (1.f / 512.f) - mean * mean, 0.f);
  const float inv = rsqrtf(var + 1e-5f);
  const float* wp = w + lane * 8;
  const float* bp = bb + lane * 8;
  float o[8];
  #pragma unroll
  for (int j = 0; j < 8; j++)
    o[j] = (v[j] - mean) * inv * wp[j] + bp[j];
  uint2 p0 = splitpk(o[0], o[1]), p1 = splitpk(o[2], o[3]);
  uint2 p2 = splitpk(o[4], o[5]), p3 = splitpk(o[6], o[7]);
  const size_t off = swz_idx(row, lane * 8, 512);
  *(int4*)(hi + off) = make_int4(p0.x, p1.x, p2.x, p3.x);
  *(int4*)(lo + off) = make_int4(p0.y, p1.y, p2.y, p3.y);
}

// ---- plain fp32 -> split planes (swizzled), no norm (head input) ---------
__global__ __launch_bounds__(256)
void split_kernel(const float* __restrict__ X, u16* __restrict__ hi,
                  u16* __restrict__ lo) {
  const int row = blockIdx.x * 4 + (threadIdx.x >> 6);
  const int lane = threadIdx.x & 63;
  const float* xp = X + (size_t)row * 512 + lane * 8;
  float v[8];
  ld4(v, xp); ld4(v + 4, xp + 4);
  uint2 p0 = splitpk(v[0], v[1]), p1 = splitpk(v[2], v[3]);
  uint2 p2 = splitpk(v[4], v[5]), p3 = splitpk(v[6], v[7]);
  const size_t off = swz_idx(row, lane * 8, 512);
  *(int4*)(hi + off) = make_int4(p0.x, p1.x, p2.x, p3.x);
  *(int4*)(lo + off) = make_int4(p0.y, p1.y, p2.y, p3.y);
}

// ---- xpos rotation + folded retention decay on Q,K (one pass) ------------
__global__ __launch_bounds__(256)
void xpos_kernel(float* __restrict__ QKV) {
  const int gid = blockIdx.x * 256 + threadIdx.x;  // R*256
  const int row = gid >> 8, r = gid & 255;
  const int h = r >> 5, i = r & 31;
  const int s = row & 255;
  const float sv = (2.0f * i + 0.4f * 64.0f) / (1.4f * 64.0f);
  const float sc = powf(sv, (float)s / 512.0f);
  const float isc = 1.0f / sc;
  const float invf = powf(10000.0f, -((float)i) / 32.0f);
  const float ang = (float)s * invf;
  const float sn = sinf(ang), cs = cosf(ang);
  const float l32 = logf(1.0f / 32.0f), l512 = logf(1.0f / 512.0f);
  const float gamma = 1.0f - expf(l32 + (float)h * (l512 - l32) / 7.0f);
  const float gq = powf(gamma, (float)s);
  const float gk = 1.0f / gq;
  const size_t base = (size_t)row * 2048 + h * 64 + 2 * i;
  const float q0 = QKV[base], q1 = QKV[base + 1];
  const float k0 = QKV[base + 512], k1 = QKV[base + 513];
  const float cq = cs * sc * gq, sq_ = sn * sc * gq;
  const float ck = cs * isc * gk, sk = sn * isc * gk;
  QKV[base]       = q0 * cq - q1 * sq_;
  QKV[base + 1]   = q1 * cq + q0 * sq_;
  QKV[base + 512] = k0 * ck - k1 * sk;
  QKV[base + 513] = k1 * ck + k0 * sk;
}

// ---- tiled causal retention attention (fp32, decay pre-folded) -----------
__global__ __launch_bounds__(256)
void attn_tiled(const float* __restrict__ QKV, float* __restrict__ Y) {
  __shared__ float Qs[64][68];   // [e][s]
  __shared__ float Ks[64][68];   // [e][m]
  __shared__ float At[64][68];   // [m][s]
  const int h = blockIdx.y;
  const int r0 = blockIdx.x * 64;       // chunk-local first row
  const int b = r0 >> 8;
  const int s0 = r0 & 255;
  const int st = s0 >> 6;               // diagonal m-tile index
  const int tid = threadIdx.x;
  const int ty = tid >> 4, tx = tid & 15;

  {  // stage Q transposed
    const int rr = tid >> 2, e0 = (tid & 3) * 16;
    const float* qp = QKV + (size_t)(r0 + rr) * 2048 + h * 64 + e0;
    #pragma unroll
    for (int j = 0; j < 16; j++) Qs[e0 + j][rr] = qp[j];
  }

  float acc2[4][8];
  #pragma unroll
  for (int i = 0; i < 4; i++)
    #pragma unroll
    for (int j = 0; j < 8; j++) acc2[i][j] = 0.f;

  for (int mt = 0; mt <= st; mt++) {
    const int m0 = mt * 64;
    {  // stage K tile transposed
      const int rr = tid >> 2, e0 = (tid & 3) * 16;
      const float* kp = QKV + (size_t)(b * 256 + m0 + rr) * 2048 + 512 + h * 64 + e0;
      #pragma unroll
      for (int j = 0; j < 16; j++) Ks[e0 + j][rr] = kp[j];
    }
    __syncthreads();
    float a1[4][4];
    #pragma unroll
    for (int i = 0; i < 4; i++)
      #pragma unroll
      for (int j = 0; j < 4; j++) a1[i][j] = 0.f;
    #pragma unroll 4
    for (int e = 0; e < 64; e++) {
      float qa[4], kb[4];
      ld4(qa, &Qs[e][ty * 4]);
      ld4(kb, &Ks[e][tx * 4]);
      #pragma unroll
      for (int i = 0; i < 4; i++)
        #pragma unroll
        for (int j = 0; j < 4; j++)
          a1[i][j] = fmaf(qa[i], kb[j], a1[i][j]);
    }
    #pragma unroll
    for (int i = 0; i < 4; i++)
      #pragma unroll
      for (int j = 0; j < 4; j++) {
        float v = a1[i][j];
        if (mt == st && (m0 + tx * 4 + j) > (s0 + ty * 4 + i)) v = 0.f;
        At[tx * 4 + j][ty * 4 + i] = v;
      }
    __syncthreads();
    const float* vp = QKV + (size_t)(b * 256 + m0) * 2048 + 1024 + h * 128 + tx * 8;
    #pragma unroll 4
    for (int m = 0; m < 64; m++) {
      float av[4], vv[8];
      ld4(av, &At[m][ty * 4]);
      ld4(vv, vp);
      ld4(vv + 4, vp + 4);
      vp += 2048;
      #pragma unroll
      for (int i = 0; i < 4; i++)
        #pragma unroll
        for (int j = 0; j < 8; j++)
          acc2[i][j] = fmaf(av[i], vv[j], acc2[i][j]);
    }
    __syncthreads();
  }
  #pragma unroll
  for (int i = 0; i < 4; i++) {
    float* yp = Y + (size_t)(r0 + ty * 4 + i) * 1024 + h * 128 + tx * 8;
    st4(yp, &acc2[i][0]);
    st4(yp + 4, &acc2[i][4]);
  }
}

// ---- group norm over 128 per (row,h), in place + affine ------------------
__global__ __launch_bounds__(256)
void gn_kernel(float* __restrict__ Y, const float* __restrict__ w,
               const float* __restrict__ bb) {
  const int wave = threadIdx.x >> 6, lane = threadIdx.x & 63;
  #pragma unroll
  for (int rep = 0; rep < 4; rep++) {
    const int grp = blockIdx.x * 16 + wave * 4 + rep;   // srow*8 + h
    const int h = grp & 7;
    float* yp = Y + (size_t)grp * 128 + lane * 2;
    const float y0 = yp[0], y1 = yp[1];
    const float s = wredf(y0 + y1);
    const float sq = wredf(y0 * y0 + y1 * y1);
    const float mean = s * (1.f / 128.f);
    const float var = fmaxf(sq * (1.f / 128.f) - mean * mean, 0.f);
    const float inv = rsqrtf(var + 1e-5f);
    const int vi = h * 128 + lane * 2;
    yp[0] = (y0 - mean) * inv * w[vi] + bb[vi];
    yp[1] = (y1 - mean) * inv * w[vi + 1] + bb[vi + 1];
  }
}

// ---- final N=1 dot (fp32) ------------------------------------------------
__global__ __launch_bounds__(256)
void head3_kernel(const float* __restrict__ X, const float* __restrict__ w,
                  const float* __restrict__ b3, float* __restrict__ out) {
  const int row = blockIdx.x * 4 + (threadIdx.x >> 6);
  const int lane = threadIdx.x & 63;
  const float* xp = X + (size_t)row * 512 + lane * 8;
  const float* wp = w + lane * 8;
  float s = 0.f;
  #pragma unroll
  for (int j = 0; j < 8; j++) s += xp[j] * wp[j];
  s = wredf(s);
  if (lane == 0) out[row] = s + b3[0];
}

// ---- weight pre-pack: W[K][N] -> swizzled Bt_hi/Bt_lo [N][K] bf16 --------
__global__ __launch_bounds__(256)
void pack_plain(const float* __restrict__ W, u16* __restrict__ hi,
                u16* __restrict__ lo, int N, int kshift) {
  const int idx = blockIdx.x * 256 + threadIdx.x;   // n*K + k (logical)
  const int K = 1 << kshift;
  const int n = idx >> kshift, k = idx & (K - 1);
  const float v = W[(size_t)k * N + n];
  const unsigned int h = bfh16(v);
  const float l = v - __uint_as_float(h << 16);
  const size_t o = swz_idx(n, k, K);
  hi[o] = (u16)h;
  lo[o] = (u16)bfh16(l);
}

// QKV head-interleaved mapping: col c<512 -> WQ(h,k,e), <1024 -> WK, else WV
__global__ __launch_bounds__(256)
void pack_qkv(const float* __restrict__ WQ, const float* __restrict__ WK,
              const float* __restrict__ WV, u16* __restrict__ hi,
              u16* __restrict__ lo) {
  const int idx = blockIdx.x * 256 + threadIdx.x;   // c*512 + k (logical)
  const int c = idx >> 9, k = idx & 511;
  float v;
  if (c < 512)
    v = WQ[((size_t)(c >> 6) * 512 + k) * 64 + (c & 63)];
  else if (c < 1024)
    v = WK[((size_t)((c - 512) >> 6) * 512 + k) * 64 + ((c - 512) & 63)];
  else
    v = WV[((size_t)((c - 1024) >> 7) * 512 + k) * 128 + ((c - 1024) & 127)];
  const unsigned int h = bfh16(v);
  const float l = v - __uint_as_float(h << 16);
  const size_t o = swz_idx(c, k, 512);
  hi[o] = (u16)h;
  lo[o] = (u16)bfh16(l);
}

// ---- bf16x3 MFMA GEMM, dbuf global_load_lds + swizzled frag reads --------
// A pre-split swizzled [M][K] hi/lo planes; B pre-packed swizzled [N][K].
// 128x128 tile, BK=32, 4 waves; LDS 2 x 4planes x [128][32] (64 KiB).
// K-step t: issue stage(t+1) -> frag-read(t) -> 48 MFMA -> barrier.
// acc += ah*bh + ah*bl + al*bh.
// EPI 0: store    1: silu(acc)*aux     2: acc+aux
//     3: gelu(acc+bias)   4: acc+bias+aux   5: w0*sin(acc+b)+w1*cos(acc+b)
// OSPLIT 0: fp32 C.  1: swizzled split bf16 planes Ch/Cl.
template<int EPI, int OSPLIT>
__global__ __launch_bounds__(256, 2)
void gemm_lds(const u16* __restrict__ Agh, const u16* __restrict__ Agl,
              const u16* __restrict__ Bh, const u16* __restrict__ Bl,
              float* __restrict__ C, u16* __restrict__ Ch, u16* __restrict__ Cl,
              const int N, const int K,
              const float* __restrict__ bias, const float* __restrict__ aux,
              const float* __restrict__ wave2) {
  __shared__ __align__(16) u16 S[2][4][128][32];   // dbuf x {Ah,Al,Bh,Bl}
  const int tid = threadIdx.x;
  const int lane = tid & 63;
  const int wave = tid >> 6;
  const int wr = (wave >> 1) * 64, wc = (wave & 1) * 64;
  const int m0 = blockIdx.y * 128, n0 = blockIdx.x * 128;

  const int fm = lane & 15;
  const int q = lane >> 4;            // logical 16B chunk 0..3

  // staging: wave w owns plane w; lane -> (row = i*16 + lane/4, 16B chunk
  // lane&3); LDS dest = linear lane*16B (HW constraint).
  const u16* pb;
  if (wave == 0)      pb = Agh + (size_t)m0 * K;
  else if (wave == 1) pb = Agl + (size_t)m0 * K;
  else if (wave == 2) pb = Bh + (size_t)n0 * K;
  else                pb = Bl + (size_t)n0 * K;
  const u16* src0 = pb + (size_t)(lane >> 2) * K + (lane & 3) * 8;

  f32x4 acc[4][4];
  #pragma unroll
  for (int i = 0; i < 4; i++)
    #pragma unroll
    for (int j = 0; j < 4; j++)
      acc[i][j] = (f32x4){0.f, 0.f, 0.f, 0.f};

  {  // prologue: stage tile 0 into buf 0
    u16* dst = &S[0][wave][0][0];
    #pragma unroll
    for (int i = 0; i < 8; i++)
      gload_lds16(src0 + (size_t)(i * 16) * K, dst + i * 512);
  }
  __syncthreads();

  for (int kt = 0; kt < K; kt += 32) {
    const int cur = (kt >> 5) & 1;
    if (kt + 32 < K) {  // issue next tile's loads; latency hides under MFMA
      u16* dst = &S[cur ^ 1][wave][0][0];
      const u16* s = src0 + kt + 32;
      #pragma unroll
      for (int i = 0; i < 8; i++)
        gload_lds16(s + (size_t)(i * 16) * K, dst + i * 512);
    }
    bf16x8 avh[4], avl[4];
    #pragma unroll
    for (int mf = 0; mf < 4; mf++) {
      const int m = wr + mf * 16 + fm;
      const int c = (q ^ ((m >> 1) & 3)) * 8;   // swizzled read
      avh[mf] = *(const bf16x8*)&S[cur][0][m][c];
      avl[mf] = *(const bf16x8*)&S[cur][1][m][c];
    }
    #pragma unroll
    for (int nf = 0; nf < 4; nf++) {
      const int n = wc + nf * 16 + fm;
      const int c = (q ^ ((n >> 1) & 3)) * 8;
      bf16x8 bh = *(const bf16x8*)&S[cur][2][n][c];
      bf16x8 bl = *(const bf16x8*)&S[cur][3][n][c];
      #pragma unroll
      for (int mf = 0; mf < 4; mf++) {
        acc[mf][nf] = __builtin_amdgcn_mfma_f32_16x16x32_bf16(avh[mf], bh, acc[mf][nf], 0, 0, 0);
        acc[mf][nf] = __builtin_amdgcn_mfma_f32_16x16x32_bf16(avl[mf], bh, acc[mf][nf], 0, 0, 0);
        acc[mf][nf] = __builtin_amdgcn_mfma_f32_16x16x32_bf16(avh[mf], bl, acc[mf][nf], 0, 0, 0);
      }
    }
    __syncthreads();   // drains prefetch (most latency already covered)
  }

  // epilogue: D frag: col = lane&15, row = (lane>>4)*4 + r
  const int r0 = m0 + wr + (lane >> 4) * 4;
  const int c0 = n0 + wc + fm;
  #pragma unroll
  for (int mf = 0; mf < 4; mf++) {
    #pragma unroll
    for (int nf = 0; nf < 4; nf++) {
      const int col = c0 + nf * 16;
      #pragma unroll
      for (int r = 0; r < 4; r++) {
        const int row = r0 + mf * 16 + r;
        const size_t idx = (size_t)row * N + col;   // logical (C, aux)
        float v = acc[mf][nf][r];
        float o;
        if constexpr (EPI == 0) {
          o = v;
        } else if constexpr (EPI == 1) {
          const float g = v / (1.f + expf(-v));
          o = g * aux[idx];
        } else if constexpr (EPI == 2) {
          o = v + aux[idx];
        } else if constexpr (EPI == 3) {
          v += bias[col];
          o = 0.5f * v * (1.f + erff(v * 0.70710678118654752f));
        } else if constexpr (EPI == 4) {
          o = v + bias[col] + aux[idx];
        } else {
          v += bias[col];
          o = wave2[0] * sinf(v) + wave2[1] * cosf(v);
        }
        if constexpr (OSPLIT == 0) {
          C[idx] = o;
        } else {
          const size_t sidx = swz_idx(row, col, N);
          const unsigned int hb = bfh16(o);
          Ch[sidx] = (u16)hb;
          Cl[sidx] = (u16)bfh16(o - __uint_as_float(hb << 16));
        }
      }
    }
  }
}

// ---- launch --------------------------------------------------------------

extern "C" void kernel_launch(void* const* d_in, const int* in_sizes, int n_in,
                              void* d_out, int out_size, void* d_ws, size_t ws_size,
                              hipStream_t stream) {
  (void)in_sizes; (void)n_in; (void)out_size;
  const float* x    = (const float*)d_in[0];
  const float* t    = (const float*)d_in[1];
  const float* embW = (const float*)d_in[2];
  const float* embB = (const float*)d_in[3];
  const float* ln1w = (const float*)d_in[4];
  const float* ln1b = (const float*)d_in[5];
  const float* ln2w = (const float*)d_in[6];
  const float* ln2b = (const float*)d_in[7];
  const float* WQ   = (const float*)d_in[8];
  const float* WK   = (const float*)d_in[9];
  const float* WV   = (const float*)d_in[10];
  const float* WG   = (const float*)d_in[11];
  const float* WO   = (const float*)d_in[12];
  const float* gnw  = (const float*)d_in[13];
  const float* gnb  = (const float*)d_in[14];
  const float* f1W  = (const float*)d_in[15];
  const float* f1b  = (const float*)d_in[16];
  const float* f2W  = (const float*)d_in[17];
  const float* f2bp = (const float*)d_in[18];
  const float* h1W  = (const float*)d_in[19];
  const float* h1b  = (const float*)d_in[20];
  const float* wvw  = (const float*)d_in[21];
  const float* h2W  = (const float*)d_in[22];
  const float* h2b  = (const float*)d_in[23];
  const float* h3W  = (const float*)d_in[24];
  const float* h3b  = (const float*)d_in[25];

  // ---- packed-weight area (bf16 hi/lo, swizzled [N][K]) ----
  u16* P = (u16*)d_ws;
  const size_t SQKV = 2048 * 512, SWG = 1024 * 512, SWO = 512 * 1024;
  const size_t SF1 = 128 * 512, SF2 = 512 * 128;
  const size_t PERL = 2 * (SQKV + SWG + SWO + SF1 + SF2);
  const size_t HOFF = 4 * PERL;                 // heads after layers
  const size_t PACK_BYTES = (HOFF + 4 * 512 * 512) * 2;  // = 37748736

  u16* h1h = P + HOFF;
  u16* h1l = h1h + 512 * 512;
  u16* h2h = h1l + 512 * 512;
  u16* h2l = h2h + 512 * 512;

  const dim3 blk(256);

  // pack all weights once
  for (int l = 0; l < 4; l++) {
    u16* qkvh = P + l * PERL;
    u16* qkvl = qkvh + SQKV;
    u16* wgh  = qkvl + SQKV;
    u16* wgl  = wgh + SWG;
    u16* woh  = wgl + SWG;
    u16* wol  = woh + SWO;
    u16* f1h  = wol + SWO;
    u16* f1l  = f1h + SF1;
    u16* f2h  = f1l + SF1;
    u16* f2l  = f2h + SF2;
    pack_qkv<<<dim3(SQKV / 256), blk, 0, stream>>>(
        WQ + (size_t)l * 262144, WK + (size_t)l * 262144,
        WV + (size_t)l * 524288, qkvh, qkvl);
    pack_plain<<<dim3(SWG / 256), blk, 0, stream>>>(WG + (size_t)l * 524288, wgh, wgl, 1024, 9);
    pack_plain<<<dim3(SWO / 256), blk, 0, stream>>>(WO + (size_t)l * 524288, woh, wol, 512, 10);
    pack_plain<<<dim3(SF1 / 256), blk, 0, stream>>>(f1W + (size_t)l * 65536, f1h, f1l, 128, 9);
    pack_plain<<<dim3(SF2 / 256), blk, 0, stream>>>(f2W + (size_t)l * 65536, f2h, f2l, 512, 7);
  }
  pack_plain<<<dim3(1024), blk, 0, stream>>>(h1W, h1h, h1l, 512, 9);
  pack_plain<<<dim3(1024), blk, 0, stream>>>(h2W, h2h, h2l, 512, 9);

  // ---- batch-chunking so fp32 activations fit after the pack area ----
  int NC = 1;
  while (NC < 256) {
    const size_t R = 65536u / NC;
    if (PACK_BYTES + R * 18432 + 4096 <= ws_size) break;
    NC <<= 1;
  }
  const int R = 65536 / NC;   // rows per chunk (multiple of 256)

  float* Xf   = (float*)((char*)d_ws + PACK_BYTES);  // R x 512 residual
  float* Xn   = Xf  + (size_t)R * 512;   // R x 512   slot: LN planes
  float* QKVb = Xn  + (size_t)R * 512;   // R x 2048  QKV fp32; later GY planes
  float* Yb   = QKVb + (size_t)R * 2048; // R x 1024  Y fp32 / mid planes / H1
  float* Yr   = Yb  + (size_t)R * 1024;  // R x 512   Yr residual / H2 fp32

  u16* Xnh = (u16*)Xn;           u16* Xnl = Xnh + (size_t)R * 512;
  u16* GYh = (u16*)QKVb;         u16* GYl = GYh + (size_t)R * 1024;
  u16* midh = (u16*)Yb;          u16* midl = midh + (size_t)R * 128;
  u16* H1h = (u16*)Yb;           u16* H1l = H1h + (size_t)R * 512;

  for (int c = 0; c < NC; c++) {
    const size_t off = (size_t)c * R;
    embed_kernel<<<dim3(R / 4), blk, 0, stream>>>(x + off, t + off, embW, embB, Xf);

    for (int l = 0; l < 4; l++) {
      u16* qkvh = P + l * PERL;
      u16* qkvl = qkvh + SQKV;
      u16* wgh  = qkvl + SQKV;
      u16* wgl  = wgh + SWG;
      u16* woh  = wgl + SWG;
      u16* wol  = woh + SWO;
      u16* f1h  = wol + SWO;
      u16* f1l  = f1h + SF1;
      u16* f2h  = f1l + SF1;
      u16* f2l  = f2h + SF2;

      ln_split<<<dim3(R / 4), blk, 0, stream>>>(Xf, ln1w + l * 512, ln1b + l * 512, Xnh, Xnl);
      // QKV = Xn @ [WQ|WK|WV][l]  (fp32 out)
      gemm_lds<0, 0><<<dim3(16, R / 128), blk, 0, stream>>>(
          Xnh, Xnl, qkvh, qkvl, QKVb, nullptr, nullptr,
          2048, 512, nullptr, nullptr, nullptr);
      xpos_kernel<<<dim3(R), blk, 0, stream>>>(QKVb);
      attn_tiled<<<dim3(R / 64, 8), blk, 0, stream>>>(QKVb, Yb);
      gn_kernel<<<dim3(R / 2), blk, 0, stream>>>(Yb, gnw + l * 1024, gnb + l * 1024);
      // GY = silu(Xn @ WG[l]) * Y  -> split planes in QKVb (QKV dead)
      gemm_lds<1, 1><<<dim3(8, R / 128), blk, 0, stream>>>(
          Xnh, Xnl, wgh, wgl, nullptr, GYh, GYl,
          1024, 512, nullptr, Yb, nullptr);
      // Yr = GY @ WO[l] + X
      gemm_lds<2, 0><<<dim3(4, R / 128), blk, 0, stream>>>(
          GYh, GYl, woh, wol, Yr, nullptr, nullptr,
          512, 1024, nullptr, Xf, nullptr);
      ln_split<<<dim3(R / 4), blk, 0, stream>>>(Yr, ln2w + l * 512, ln2b + l * 512, Xnh, Xnl);
      // mid = gelu(Xn @ f1[l] + b1)  -> split planes in Yb
      gemm_lds<3, 1><<<dim3(1, R / 128), blk, 0, stream>>>(
          Xnh, Xnl, f1h, f1l, nullptr, midh, midl,
          128, 512, f1b + l * 128, nullptr, nullptr);
      // X = mid @ f2[l] + b2 + Yr
      gemm_lds<4, 0><<<dim3(4, R / 128), blk, 0, stream>>>(
          midh, midl, f2h, f2l, Xf, nullptr, nullptr,
          512, 128, f2bp + l * 512, Yr, nullptr);
    }

    // head: split Xf once, then gemm_lds all the way
    split_kernel<<<dim3(R / 4), blk, 0, stream>>>(Xf, Xnh, Xnl);
    // H1 = wave(Xf @ h1W + b1) -> split planes in Yb
    gemm_lds<5, 1><<<dim3(4, R / 128), blk, 0, stream>>>(
        Xnh, Xnl, h1h, h1l, nullptr, H1h, H1l,
        512, 512, h1b, nullptr, wvw);
    // H2 = wave(H1 @ h2W + b2) -> fp32 in Yr
    gemm_lds<5, 0><<<dim3(4, R / 128), blk, 0, stream>>>(
        H1h, H1l, h2h, h2l, Yr, nullptr, nullptr,
        512, 512, h2b, nullptr, wvw + 2);
    head3_kernel<<<dim3(R / 4), blk, 0, stream>>>(
        Yr, h3W, h3b, (float*)d_out + off);
  }
}

// Round 6
// 11271.600 us; speedup vs baseline: 1.9035x; 1.0608x over previous
//
#include <hip/hip_runtime.h>
#include <cstdint>
#include <cstddef>

#define DEV static __device__ __forceinline__

typedef short bf16x8 __attribute__((ext_vector_type(8)));
typedef float f32x4 __attribute__((ext_vector_type(4)));
typedef unsigned short u16;

DEV float wredf(float v) {
  v += __shfl_xor(v, 32, 64); v += __shfl_xor(v, 16, 64);
  v += __shfl_xor(v, 8, 64);  v += __shfl_xor(v, 4, 64);
  v += __shfl_xor(v, 2, 64);  v += __shfl_xor(v, 1, 64);
  return v;
}

DEV void ld4(float* d, const float* p) {
  float4 t = *(const float4*)p;
  d[0] = t.x; d[1] = t.y; d[2] = t.z; d[3] = t.w;
}
DEV void st4(float* p, const float* s) {
  *(float4*)p = make_float4(s[0], s[1], s[2], s[3]);
}

// round-to-nearest-even fp32 -> bf16 bits
DEV unsigned int bfh16(float v) {
  unsigned int u = __float_as_uint(v);
  return (u + 0x7FFFu + ((u >> 16) & 1u)) >> 16;
}
// split pair (a,b) -> packed hi-word / lo-word (2x bf16 each)
DEV uint2 splitpk(float a, float b) {
  unsigned int ha = bfh16(a), hb = bfh16(b);
  float la = a - __uint_as_float(ha << 16);
  float lb = b - __uint_as_float(hb << 16);
  return make_uint2(ha | (hb << 16), bfh16(la) | (bfh16(lb) << 16));
}

// T2 swizzle for plane buffers: within each 32-elem k-segment, 16B chunk
// c -> c ^ ((row>>1)&3).  Writers store swizzled; gemm_lds reads swizzled;
// global_load_lds stages linearly (rule #21).
DEV size_t swz_idx(int row, int col, int ld) {
  return (size_t)row * ld + (col & ~31) +
         ((((col >> 3) & 3) ^ ((row >> 1) & 3)) << 3) + (col & 7);
}

// async global->LDS, 16B per lane: LDS dest = base + lane*16 (HW)
DEV void gload_lds16(const void* g, void* l) {
  __builtin_amdgcn_global_load_lds(
      (const __attribute__((address_space(1))) unsigned int*)g,
      (__attribute__((address_space(3))) unsigned int*)l, 16, 0, 0);
}

// ---- rotation/decay tables (once per launch) -----------------------------
// floats: [0,16384) rotq (s*32+i)*2 = {cos*sc, sin*sc}
//         [16384,32768) rotk = {cos/sc, sin/sc}
//         [32768,34816) gq[h][s] = gamma_h^s
//         [34816,36864) gk[h][s] = gamma_h^-s
__global__ __launch_bounds__(256)
void tab_kernel(float* __restrict__ rtab) {
  const int idx = blockIdx.x * 256 + threadIdx.x;
  if (idx < 16384) {
    const int tk = idx >> 13;          // 0=q, 1=k
    const int e = idx & 8191;
    const int s = e >> 5, i = e & 31;
    const float sv = (2.0f * i + 25.6f) / 89.6f;
    const float sc = powf(sv, (float)s / 512.0f);
    const float invf = powf(10000.0f, -(float)i / 32.0f);
    const float ang = (float)s * invf;
    const float f = tk ? 1.0f / sc : sc;
    rtab[tk * 16384 + e * 2]     = cosf(ang) * f;
    rtab[tk * 16384 + e * 2 + 1] = sinf(ang) * f;
  } else if (idx < 20480) {
    const int e = idx - 16384;         // 0..4095
    const int tk = e >> 11;            // 0=gq, 1=gk
    const int he = e & 2047;
    const int h = he >> 8, s = he & 255;
    const float l32 = logf(1.0f / 32.0f), l512 = logf(1.0f / 512.0f);
    const float gamma = 1.0f - expf(l32 + (float)h * (l512 - l32) / 7.0f);
    const float g = powf(gamma, (float)s);
    rtab[32768 + e] = tk ? 1.0f / g : g;
  }
}

// ---- embed: src = [x,t] @ emb_W + emb_b  (fp32) --------------------------
__global__ __launch_bounds__(256)
void embed_kernel(const float* __restrict__ x, const float* __restrict__ t,
                  const float* __restrict__ W, const float* __restrict__ eb,
                  float* __restrict__ X) {
  const int gid = blockIdx.x * 256 + threadIdx.x;  // R*64
  const int row = gid >> 6, d = (gid & 63) * 8;
  const float xv = x[row], tv = t[row];
  #pragma unroll
  for (int j = 0; j < 8; j++)
    X[(size_t)row * 512 + d + j] =
        xv * W[d + j] + tv * W[512 + d + j] + eb[d + j];
}

// ---- layernorm row=512, fp32 -> split bf16 hi/lo planes (swizzled) -------
__global__ __launch_bounds__(256)
void ln_split(const float* __restrict__ X, const float* __restrict__ w,
              const float* __restrict__ bb, u16* __restrict__ hi,
              u16* __restrict__ lo) {
  const int row = blockIdx.x * 4 + (threadIdx.x >> 6);
  const int lane = threadIdx.x & 63;
  const float* xp = X + (size_t)row * 512 + lane * 8;
  float4 a0 = *(const float4*)xp;
  float4 a1 = *(const float4*)(xp + 4);
  float v[8] = {a0.x, a0.y, a0.z, a0.w, a1.x, a1.y, a1.z, a1.w};
  float s = 0.f, sq = 0.f;
  #pragma unroll
  for (int j = 0; j < 8; j++) { s += v[j]; sq += v[j] * v[j]; }
  s = wredf(s); sq = wredf(sq);
  const float mean = s * (1.f / 512.f);
  const float var = fmaxf(sq * (1.f / 512.f) - mean * mean, 0.f);
  const float inv = rsqrtf(var + 1e-5f);
  const float* wp = w + lane * 8;
  const float* bp = bb + lane * 8;
  float o[8];
  #pragma unroll
  for (int j = 0; j < 8; j++)
    o[j] = (v[j] - mean) * inv * wp[j] + bp[j];
  uint2 p0 = splitpk(o[0], o[1]), p1 = splitpk(o[2], o[3]);
  uint2 p2 = splitpk(o[4], o[5]), p3 = splitpk(o[6], o[7]);
  const size_t off = swz_idx(row, lane * 8, 512);
  *(int4*)(hi + off) = make_int4(p0.x, p1.x, p2.x, p3.x);
  *(int4*)(lo + off) = make_int4(p0.y, p1.y, p2.y, p3.y);
}

// ---- plain fp32 -> split planes (swizzled), no norm (head input) ---------
__global__ __launch_bounds__(256)
void split_kernel(const float* __restrict__ X, u16* __restrict__ hi,
                  u16* __restrict__ lo) {
  const int row = blockIdx.x * 4 + (threadIdx.x >> 6);
  const int lane = threadIdx.x & 63;
  const float* xp = X + (size_t)row * 512 + lane * 8;
  float v[8];
  ld4(v, xp); ld4(v + 4, xp + 4);
  uint2 p0 = splitpk(v[0], v[1]), p1 = splitpk(v[2], v[3]);
  uint2 p2 = splitpk(v[4], v[5]), p3 = splitpk(v[6], v[7]);
  const size_t off = swz_idx(row, lane * 8, 512);
  *(int4*)(hi + off) = make_int4(p0.x, p1.x, p2.x, p3.x);
  *(int4*)(lo + off) = make_int4(p0.y, p1.y, p2.y, p3.y);
}

// ---- tiled causal retention attention + fused groupnorm ------------------
// QKV row: [Q(512) K(512) V(1024)], Q/K already rotated+decayed by the GEMM
// epilogue. Epilogue: group-norm over 128 v-dims per (row,h) + affine.
__global__ __launch_bounds__(256)
void attn_fused(const float* __restrict__ QKV, float* __restrict__ Y,
                const float* __restrict__ gw, const float* __restrict__ gb) {
  __shared__ float Qs[64][68];   // [e][s]
  __shared__ float Ks[64][68];   // [e][m]
  __shared__ float At[64][68];   // [m][s]
  const int h = blockIdx.y;
  const int r0 = blockIdx.x * 64;       // chunk-local first row
  const int b = r0 >> 8;
  const int s0 = r0 & 255;
  const int st = s0 >> 6;               // diagonal m-tile index
  const int tid = threadIdx.x;
  const int ty = tid >> 4, tx = tid & 15;

  {  // stage Q transposed
    const int rr = tid >> 2, e0 = (tid & 3) * 16;
    const float* qp = QKV + (size_t)(r0 + rr) * 2048 + h * 64 + e0;
    #pragma unroll
    for (int j = 0; j < 16; j++) Qs[e0 + j][rr] = qp[j];
  }

  float acc2[4][8];
  #pragma unroll
  for (int i = 0; i < 4; i++)
    #pragma unroll
    for (int j = 0; j < 8; j++) acc2[i][j] = 0.f;

  for (int mt = 0; mt <= st; mt++) {
    const int m0 = mt * 64;
    {  // stage K tile transposed
      const int rr = tid >> 2, e0 = (tid & 3) * 16;
      const float* kp = QKV + (size_t)(b * 256 + m0 + rr) * 2048 + 512 + h * 64 + e0;
      #pragma unroll
      for (int j = 0; j < 16; j++) Ks[e0 + j][rr] = kp[j];
    }
    __syncthreads();
    float a1[4][4];
    #pragma unroll
    for (int i = 0; i < 4; i++)
      #pragma unroll
      for (int j = 0; j < 4; j++) a1[i][j] = 0.f;
    #pragma unroll 4
    for (int e = 0; e < 64; e++) {
      float qa[4], kb[4];
      ld4(qa, &Qs[e][ty * 4]);
      ld4(kb, &Ks[e][tx * 4]);
      #pragma unroll
      for (int i = 0; i < 4; i++)
        #pragma unroll
        for (int j = 0; j < 4; j++)
          a1[i][j] = fmaf(qa[i], kb[j], a1[i][j]);
    }
    #pragma unroll
    for (int i = 0; i < 4; i++)
      #pragma unroll
      for (int j = 0; j < 4; j++) {
        float v = a1[i][j];
        if (mt == st && (m0 + tx * 4 + j) > (s0 + ty * 4 + i)) v = 0.f;
        At[tx * 4 + j][ty * 4 + i] = v;
      }
    __syncthreads();
    const float* vp = QKV + (size_t)(b * 256 + m0) * 2048 + 1024 + h * 128 + tx * 8;
    #pragma unroll 4
    for (int m = 0; m < 64; m++) {
      float av[4], vv[8];
      ld4(av, &At[m][ty * 4]);
      ld4(vv, vp);
      ld4(vv + 4, vp + 4);
      vp += 2048;
      #pragma unroll
      for (int i = 0; i < 4; i++)
        #pragma unroll
        for (int j = 0; j < 8; j++)
          acc2[i][j] = fmaf(av[i], vv[j], acc2[i][j]);
    }
    __syncthreads();
  }

  // fused group-norm epilogue: per row, reduce over the 16-lane tx group
  const int vi = h * 128 + tx * 8;
  float gwv[8], gbv[8];
  ld4(gwv, gw + vi); ld4(gwv + 4, gw + vi + 4);
  ld4(gbv, gb + vi); ld4(gbv + 4, gb + vi + 4);
  #pragma unroll
  for (int i = 0; i < 4; i++) {
    float s = 0.f, sq = 0.f;
    #pragma unroll
    for (int j = 0; j < 8; j++) { s += acc2[i][j]; sq += acc2[i][j] * acc2[i][j]; }
    #pragma unroll
    for (int msk = 1; msk <= 8; msk <<= 1) {
      s += __shfl_xor(s, msk, 64);
      sq += __shfl_xor(sq, msk, 64);
    }
    const float mean = s * (1.f / 128.f);
    const float var = fmaxf(sq * (1.f / 128.f) - mean * mean, 0.f);
    const float inv = rsqrtf(var + 1e-5f);
    float o[8];
    #pragma unroll
    for (int j = 0; j < 8; j++)
      o[j] = (acc2[i][j] - mean) * inv * gwv[j] + gbv[j];
    float* yp = Y + (size_t)(r0 + ty * 4 + i) * 1024 + vi;
    st4(yp, o);
    st4(yp + 4, o + 4);
  }
}

// ---- final N=1 dot (fp32) ------------------------------------------------
__global__ __launch_bounds__(256)
void head3_kernel(const float* __restrict__ X, const float* __restrict__ w,
                  const float* __restrict__ b3, float* __restrict__ out) {
  const int row = blockIdx.x * 4 + (threadIdx.x >> 6);
  const int lane = threadIdx.x & 63;
  const float* xp = X + (size_t)row * 512 + lane * 8;
  const float* wp = w + lane * 8;
  float s = 0.f;
  #pragma unroll
  for (int j = 0; j < 8; j++) s += xp[j] * wp[j];
  s = wredf(s);
  if (lane == 0) out[row] = s + b3[0];
}

// ---- weight pre-pack: W[K][N] -> swizzled Bt_hi/Bt_lo [N][K] bf16 --------
__global__ __launch_bounds__(256)
void pack_plain(const float* __restrict__ W, u16* __restrict__ hi,
                u16* __restrict__ lo, int N, int kshift) {
  const int idx = blockIdx.x * 256 + threadIdx.x;   // n*K + k (logical)
  const int K = 1 << kshift;
  const int n = idx >> kshift, k = idx & (K - 1);
  const float v = W[(size_t)k * N + n];
  const unsigned int h = bfh16(v);
  const float l = v - __uint_as_float(h << 16);
  const size_t o = swz_idx(n, k, K);
  hi[o] = (u16)h;
  lo[o] = (u16)bfh16(l);
}

// QKV head-interleaved mapping: col c<512 -> WQ(h,k,e), <1024 -> WK, else WV
__global__ __launch_bounds__(256)
void pack_qkv(const float* __restrict__ WQ, const float* __restrict__ WK,
              const float* __restrict__ WV, u16* __restrict__ hi,
              u16* __restrict__ lo) {
  const int idx = blockIdx.x * 256 + threadIdx.x;   // c*512 + k (logical)
  const int c = idx >> 9, k = idx & 511;
  float v;
  if (c < 512)
    v = WQ[((size_t)(c >> 6) * 512 + k) * 64 + (c & 63)];
  else if (c < 1024)
    v = WK[((size_t)((c - 512) >> 6) * 512 + k) * 64 + ((c - 512) & 63)];
  else
    v = WV[((size_t)((c - 1024) >> 7) * 512 + k) * 128 + ((c - 1024) & 127)];
  const unsigned int h = bfh16(v);
  const float l = v - __uint_as_float(h << 16);
  const size_t o = swz_idx(c, k, 512);
  hi[o] = (u16)h;
  lo[o] = (u16)bfh16(l);
}

// ---- bf16x3 MFMA GEMM, dbuf global_load_lds + swizzled frag reads --------
// EPI 0: store    1: silu(acc)*aux     2: acc+aux
//     3: gelu(acc+bias)   4: acc+bias+aux   5: w0*sin(acc+b)+w1*cos(acc+b)
//     6: QKV xpos-rotation + retention decay via rtab (V pass-through)
// OSPLIT 0: fp32 C.  1: swizzled split bf16 planes Ch/Cl.
template<int EPI, int OSPLIT>
__global__ __launch_bounds__(256, 2)
void gemm_lds(const u16* __restrict__ Agh, const u16* __restrict__ Agl,
              const u16* __restrict__ Bh, const u16* __restrict__ Bl,
              float* __restrict__ C, u16* __restrict__ Ch, u16* __restrict__ Cl,
              const int N, const int K,
              const float* __restrict__ bias, const float* __restrict__ aux,
              const float* __restrict__ wave2, const float* __restrict__ rtab) {
  __shared__ __align__(16) u16 S[2][4][128][32];   // dbuf x {Ah,Al,Bh,Bl}
  const int tid = threadIdx.x;
  const int lane = tid & 63;
  const int wave = tid >> 6;
  const int wr = (wave >> 1) * 64, wc = (wave & 1) * 64;
  const int m0 = blockIdx.y * 128, n0 = blockIdx.x * 128;

  const int fm = lane & 15;
  const int q = lane >> 4;            // logical 16B chunk 0..3

  const u16* pb;
  if (wave == 0)      pb = Agh + (size_t)m0 * K;
  else if (wave == 1) pb = Agl + (size_t)m0 * K;
  else if (wave == 2) pb = Bh + (size_t)n0 * K;
  else                pb = Bl + (size_t)n0 * K;
  const u16* src0 = pb + (size_t)(lane >> 2) * K + (lane & 3) * 8;

  f32x4 acc[4][4];
  #pragma unroll
  for (int i = 0; i < 4; i++)
    #pragma unroll
    for (int j = 0; j < 4; j++)
      acc[i][j] = (f32x4){0.f, 0.f, 0.f, 0.f};

  {  // prologue: stage tile 0 into buf 0
    u16* dst = &S[0][wave][0][0];
    #pragma unroll
    for (int i = 0; i < 8; i++)
      gload_lds16(src0 + (size_t)(i * 16) * K, dst + i * 512);
  }
  __syncthreads();

  for (int kt = 0; kt < K; kt += 32) {
    const int cur = (kt >> 5) & 1;
    if (kt + 32 < K) {  // issue next tile's loads; latency hides under MFMA
      u16* dst = &S[cur ^ 1][wave][0][0];
      const u16* s = src0 + kt + 32;
      #pragma unroll
      for (int i = 0; i < 8; i++)
        gload_lds16(s + (size_t)(i * 16) * K, dst + i * 512);
    }
    bf16x8 avh[4], avl[4];
    #pragma unroll
    for (int mf = 0; mf < 4; mf++) {
      const int m = wr + mf * 16 + fm;
      const int c = (q ^ ((m >> 1) & 3)) * 8;   // swizzled read
      avh[mf] = *(const bf16x8*)&S[cur][0][m][c];
      avl[mf] = *(const bf16x8*)&S[cur][1][m][c];
    }
    #pragma unroll
    for (int nf = 0; nf < 4; nf++) {
      const int n = wc + nf * 16 + fm;
      const int c = (q ^ ((n >> 1) & 3)) * 8;
      bf16x8 bh = *(const bf16x8*)&S[cur][2][n][c];
      bf16x8 bl = *(const bf16x8*)&S[cur][3][n][c];
      #pragma unroll
      for (int mf = 0; mf < 4; mf++) {
        acc[mf][nf] = __builtin_amdgcn_mfma_f32_16x16x32_bf16(avh[mf], bh, acc[mf][nf], 0, 0, 0);
        acc[mf][nf] = __builtin_amdgcn_mfma_f32_16x16x32_bf16(avl[mf], bh, acc[mf][nf], 0, 0, 0);
        acc[mf][nf] = __builtin_amdgcn_mfma_f32_16x16x32_bf16(avh[mf], bl, acc[mf][nf], 0, 0, 0);
      }
    }
    __syncthreads();
  }

  // epilogue: D frag: col = lane&15, row = (lane>>4)*4 + r
  const int r0 = m0 + wr + (lane >> 4) * 4;
  const int c0 = n0 + wc + fm;
  #pragma unroll
  for (int mf = 0; mf < 4; mf++) {
    #pragma unroll
    for (int nf = 0; nf < 4; nf++) {
      const int col = c0 + nf * 16;
      #pragma unroll
      for (int r = 0; r < 4; r++) {
        const int row = r0 + mf * 16 + r;
        const size_t idx = (size_t)row * N + col;   // logical (C, aux)
        float v = acc[mf][nf][r];
        float o;
        if constexpr (EPI == 0) {
          o = v;
        } else if constexpr (EPI == 1) {
          const float g = v / (1.f + expf(-v));
          o = g * aux[idx];
        } else if constexpr (EPI == 2) {
          o = v + aux[idx];
        } else if constexpr (EPI == 3) {
          v += bias[col];
          o = 0.5f * v * (1.f + erff(v * 0.70710678118654752f));
        } else if constexpr (EPI == 4) {
          o = v + bias[col] + aux[idx];
        } else if constexpr (EPI == 5) {
          v += bias[col];
          o = wave2[0] * sinf(v) + wave2[1] * cosf(v);
        } else {
          // EPI 6: xpos rotation + decay for Q/K cols; V pass-through.
          // partner col = col^1 lives in lane^1, same row/regs.
          const float p = __shfl_xor(v, 1, 64);
          if (col < 1024) {               // wave-uniform branch
            const int s = row & 255;
            const int cc = col & 511;
            const int hh = cc >> 6;
            const int ii = (cc & 63) >> 1;
            const bool isK = col >= 512;
            const float2 cs2 = *(const float2*)(
                rtab + (isK ? 16384 : 0) + ((size_t)s * 32 + ii) * 2);
            const float g = rtab[(isK ? 34816 : 32768) + hh * 256 + s];
            o = ((col & 1) ? (v * cs2.x + p * cs2.y)
                           : (v * cs2.x - p * cs2.y)) * g;
          } else {
            o = v;
          }
        }
        if constexpr (OSPLIT == 0) {
          C[idx] = o;
        } else {
          const size_t sidx = swz_idx(row, col, N);
          const unsigned int hb = bfh16(o);
          Ch[sidx] = (u16)hb;
          Cl[sidx] = (u16)bfh16(o - __uint_as_float(hb << 16));
        }
      }
    }
  }
}

// ---- launch --------------------------------------------------------------

extern "C" void kernel_launch(void* const* d_in, const int* in_sizes, int n_in,
                              void* d_out, int out_size, void* d_ws, size_t ws_size,
                              hipStream_t stream) {
  (void)in_sizes; (void)n_in; (void)out_size;
  const float* x    = (const float*)d_in[0];
  const float* t    = (const float*)d_in[1];
  const float* embW = (const float*)d_in[2];
  const float* embB = (const float*)d_in[3];
  const float* ln1w = (const float*)d_in[4];
  const float* ln1b = (const float*)d_in[5];
  const float* ln2w = (const float*)d_in[6];
  const float* ln2b = (const float*)d_in[7];
  const float* WQ   = (const float*)d_in[8];
  const float* WK   = (const float*)d_in[9];
  const float* WV   = (const float*)d_in[10];
  const float* WG   = (const float*)d_in[11];
  const float* WO   = (const float*)d_in[12];
  const float* gnw  = (const float*)d_in[13];
  const float* gnb  = (const float*)d_in[14];
  const float* f1W  = (const float*)d_in[15];
  const float* f1b  = (const float*)d_in[16];
  const float* f2W  = (const float*)d_in[17];
  const float* f2bp = (const float*)d_in[18];
  const float* h1W  = (const float*)d_in[19];
  const float* h1b  = (const float*)d_in[20];
  const float* wvw  = (const float*)d_in[21];
  const float* h2W  = (const float*)d_in[22];
  const float* h2b  = (const float*)d_in[23];
  const float* h3W  = (const float*)d_in[24];
  const float* h3b  = (const float*)d_in[25];

  // ---- packed-weight area (bf16 hi/lo, swizzled [N][K]) ----
  u16* P = (u16*)d_ws;
  const size_t SQKV = 2048 * 512, SWG = 1024 * 512, SWO = 512 * 1024;
  const size_t SF1 = 128 * 512, SF2 = 512 * 128;
  const size_t PERL = 2 * (SQKV + SWG + SWO + SF1 + SF2);
  const size_t HOFF = 4 * PERL;                 // heads after layers
  const size_t PACK_BYTES = (HOFF + 4 * 512 * 512) * 2;  // = 37748736
  const size_t TAB_BYTES = 36864 * 4;           // rotation/decay tables

  u16* h1h = P + HOFF;
  u16* h1l = h1h + 512 * 512;
  u16* h2h = h1l + 512 * 512;
  u16* h2l = h2h + 512 * 512;
  float* RT = (float*)((char*)d_ws + PACK_BYTES);

  const dim3 blk(256);

  // tables + pack all weights once
  tab_kernel<<<dim3(80), blk, 0, stream>>>(RT);
  for (int l = 0; l < 4; l++) {
    u16* qkvh = P + l * PERL;
    u16* qkvl = qkvh + SQKV;
    u16* wgh  = qkvl + SQKV;
    u16* wgl  = wgh + SWG;
    u16* woh  = wgl + SWG;
    u16* wol  = woh + SWO;
    u16* f1h  = wol + SWO;
    u16* f1l  = f1h + SF1;
    u16* f2h  = f1l + SF1;
    u16* f2l  = f2h + SF2;
    pack_qkv<<<dim3(SQKV / 256), blk, 0, stream>>>(
        WQ + (size_t)l * 262144, WK + (size_t)l * 262144,
        WV + (size_t)l * 524288, qkvh, qkvl);
    pack_plain<<<dim3(SWG / 256), blk, 0, stream>>>(WG + (size_t)l * 524288, wgh, wgl, 1024, 9);
    pack_plain<<<dim3(SWO / 256), blk, 0, stream>>>(WO + (size_t)l * 524288, woh, wol, 512, 10);
    pack_plain<<<dim3(SF1 / 256), blk, 0, stream>>>(f1W + (size_t)l * 65536, f1h, f1l, 128, 9);
    pack_plain<<<dim3(SF2 / 256), blk, 0, stream>>>(f2W + (size_t)l * 65536, f2h, f2l, 512, 7);
  }
  pack_plain<<<dim3(1024), blk, 0, stream>>>(h1W, h1h, h1l, 512, 9);
  pack_plain<<<dim3(1024), blk, 0, stream>>>(h2W, h2h, h2l, 512, 9);

  // ---- batch-chunking so fp32 activations fit after pack+tables ----
  const size_t BASE = PACK_BYTES + TAB_BYTES;
  int NC = 1;
  while (NC < 256) {
    const size_t R = 65536u / NC;
    if (BASE + R * 18432 + 4096 <= ws_size) break;
    NC <<= 1;
  }
  const int R = 65536 / NC;   // rows per chunk (multiple of 256)

  float* Xf   = (float*)((char*)d_ws + BASE);  // R x 512 residual
  float* Xn   = Xf  + (size_t)R * 512;   // R x 512   slot: LN planes
  float* QKVb = Xn  + (size_t)R * 512;   // R x 2048  QKV fp32; later GY planes
  float* Yb   = QKVb + (size_t)R * 2048; // R x 1024  Y fp32 / mid planes / H1
  float* Yr   = Yb  + (size_t)R * 1024;  // R x 512   Yr residual / H2 fp32

  u16* Xnh = (u16*)Xn;           u16* Xnl = Xnh + (size_t)R * 512;
  u16* GYh = (u16*)QKVb;         u16* GYl = GYh + (size_t)R * 1024;
  u16* midh = (u16*)Yb;          u16* midl = midh + (size_t)R * 128;
  u16* H1h = (u16*)Yb;           u16* H1l = H1h + (size_t)R * 512;

  for (int c = 0; c < NC; c++) {
    const size_t off = (size_t)c * R;
    embed_kernel<<<dim3(R / 4), blk, 0, stream>>>(x + off, t + off, embW, embB, Xf);

    for (int l = 0; l < 4; l++) {
      u16* qkvh = P + l * PERL;
      u16* qkvl = qkvh + SQKV;
      u16* wgh  = qkvl + SQKV;
      u16* wgl  = wgh + SWG;
      u16* woh  = wgl + SWG;
      u16* wol  = woh + SWO;
      u16* f1h  = wol + SWO;
      u16* f1l  = f1h + SF1;
      u16* f2h  = f1l + SF1;
      u16* f2l  = f2h + SF2;

      ln_split<<<dim3(R / 4), blk, 0, stream>>>(Xf, ln1w + l * 512, ln1b + l * 512, Xnh, Xnl);
      // QKV = Xn @ [WQ|WK|WV][l], rotation+decay fused in epilogue
      gemm_lds<6, 0><<<dim3(16, R / 128), blk, 0, stream>>>(
          Xnh, Xnl, qkvh, qkvl, QKVb, nullptr, nullptr,
          2048, 512, nullptr, nullptr, nullptr, RT);
      // causal retention attention + fused groupnorm
      attn_fused<<<dim3(R / 64, 8), blk, 0, stream>>>(
          QKVb, Yb, gnw + l * 1024, gnb + l * 1024);
      // GY = silu(Xn @ WG[l]) * Y  -> split planes in QKVb (QKV dead)
      gemm_lds<1, 1><<<dim3(8, R / 128), blk, 0, stream>>>(
          Xnh, Xnl, wgh, wgl, nullptr, GYh, GYl,
          1024, 512, nullptr, Yb, nullptr, nullptr);
      // Yr = GY @ WO[l] + X
      gemm_lds<2, 0><<<dim3(4, R / 128), blk, 0, stream>>>(
          GYh, GYl, woh, wol, Yr, nullptr, nullptr,
          512, 1024, nullptr, Xf, nullptr, nullptr);
      ln_split<<<dim3(R / 4), blk, 0, stream>>>(Yr, ln2w + l * 512, ln2b + l * 512, Xnh, Xnl);
      // mid = gelu(Xn @ f1[l] + b1)  -> split planes in Yb
      gemm_lds<3, 1><<<dim3(1, R / 128), blk, 0, stream>>>(
          Xnh, Xnl, f1h, f1l, nullptr, midh, midl,
          128, 512, f1b + l * 128, nullptr, nullptr, nullptr);
      // X = mid @ f2[l] + b2 + Yr
      gemm_lds<4, 0><<<dim3(4, R / 128), blk, 0, stream>>>(
          midh, midl, f2h, f2l, Xf, nullptr, nullptr,
          512, 128, f2bp + l * 512, Yr, nullptr, nullptr);
    }

    // head: split Xf once, then gemm_lds all the way
    split_kernel<<<dim3(R / 4), blk, 0, stream>>>(Xf, Xnh, Xnl);
    gemm_lds<5, 1><<<dim3(4, R / 128), blk, 0, stream>>>(
        Xnh, Xnl, h1h, h1l, nullptr, H1h, H1l,
        512, 512, h1b, nullptr, wvw, nullptr);
    gemm_lds<5, 0><<<dim3(4, R / 128), blk, 0, stream>>>(
        H1h, H1l, h2h, h2l, Yr, nullptr, nullptr,
        512, 512, h2b, nullptr, wvw + 2, nullptr);
    head3_kernel<<<dim3(R / 4), blk, 0, stream>>>(
        Yr, h3W, h3b, (float*)d_out + off);
  }
}

// Round 7
// 11181.493 us; speedup vs baseline: 1.9189x; 1.0081x over previous
//
#include <hip/hip_runtime.h>
#include <cstdint>
#include <cstddef>

#define DEV static __device__ __forceinline__

typedef short bf16x8 __attribute__((ext_vector_type(8)));
typedef float f32x4 __attribute__((ext_vector_type(4)));
typedef unsigned short u16;

DEV float wredf(float v) {
  v += __shfl_xor(v, 32, 64); v += __shfl_xor(v, 16, 64);
  v += __shfl_xor(v, 8, 64);  v += __shfl_xor(v, 4, 64);
  v += __shfl_xor(v, 2, 64);  v += __shfl_xor(v, 1, 64);
  return v;
}

DEV void ld4(float* d, const float* p) {
  float4 t = *(const float4*)p;
  d[0] = t.x; d[1] = t.y; d[2] = t.z; d[3] = t.w;
}
DEV void st4(float* p, const float* s) {
  *(float4*)p = make_float4(s[0], s[1], s[2], s[3]);
}

// round-to-nearest-even fp32 -> bf16 bits
DEV unsigned int bfh16(float v) {
  unsigned int u = __float_as_uint(v);
  return (u + 0x7FFFu + ((u >> 16) & 1u)) >> 16;
}
// split pair (a,b) -> packed hi-word / lo-word (2x bf16 each)
DEV uint2 splitpk(float a, float b) {
  unsigned int ha = bfh16(a), hb = bfh16(b);
  float la = a - __uint_as_float(ha << 16);
  float lb = b - __uint_as_float(hb << 16);
  return make_uint2(ha | (hb << 16), bfh16(la) | (bfh16(lb) << 16));
}

// T2 swizzle for plane buffers: within each 32-elem k-segment, 16B chunk
// c -> c ^ ((row>>1)&3).  Writers store swizzled; gemm_lds reads swizzled;
// global_load_lds stages linearly (rule #21).
DEV size_t swz_idx(int row, int col, int ld) {
  return (size_t)row * ld + (col & ~31) +
         ((((col >> 3) & 3) ^ ((row >> 1) & 3)) << 3) + (col & 7);
}

// async global->LDS, 16B per lane: LDS dest = base + lane*16 (HW)
DEV void gload_lds16(const void* g, void* l) {
  __builtin_amdgcn_global_load_lds(
      (const __attribute__((address_space(1))) unsigned int*)g,
      (__attribute__((address_space(3))) unsigned int*)l, 16, 0, 0);
}

// ---- rotation/decay tables (once per launch) -----------------------------
// floats: [0,16384) rotq (s*32+i)*2 = {cos*sc, sin*sc}
//         [16384,32768) rotk = {cos/sc, sin/sc}
//         [32768,34816) gq[h][s] = gamma_h^s
//         [34816,36864) gk[h][s] = gamma_h^-s
__global__ __launch_bounds__(256)
void tab_kernel(float* __restrict__ rtab) {
  const int idx = blockIdx.x * 256 + threadIdx.x;
  if (idx < 16384) {
    const int tk = idx >> 13;          // 0=q, 1=k
    const int e = idx & 8191;
    const int s = e >> 5, i = e & 31;
    const float sv = (2.0f * i + 25.6f) / 89.6f;
    const float sc = powf(sv, (float)s / 512.0f);
    const float invf = powf(10000.0f, -(float)i / 32.0f);
    const float ang = (float)s * invf;
    const float f = tk ? 1.0f / sc : sc;
    rtab[tk * 16384 + e * 2]     = cosf(ang) * f;
    rtab[tk * 16384 + e * 2 + 1] = sinf(ang) * f;
  } else if (idx < 20480) {
    const int e = idx - 16384;         // 0..4095
    const int tk = e >> 11;            // 0=gq, 1=gk
    const int he = e & 2047;
    const int h = he >> 8, s = he & 255;
    const float l32 = logf(1.0f / 32.0f), l512 = logf(1.0f / 512.0f);
    const float gamma = 1.0f - expf(l32 + (float)h * (l512 - l32) / 7.0f);
    const float g = powf(gamma, (float)s);
    rtab[32768 + e] = tk ? 1.0f / g : g;
  }
}

// ---- embed: src = [x,t] @ emb_W + emb_b  (fp32) --------------------------
__global__ __launch_bounds__(256)
void embed_kernel(const float* __restrict__ x, const float* __restrict__ t,
                  const float* __restrict__ W, const float* __restrict__ eb,
                  float* __restrict__ X) {
  const int gid = blockIdx.x * 256 + threadIdx.x;  // R*64
  const int row = gid >> 6, d = (gid & 63) * 8;
  const float xv = x[row], tv = t[row];
  #pragma unroll
  for (int j = 0; j < 8; j++)
    X[(size_t)row * 512 + d + j] =
        xv * W[d + j] + tv * W[512 + d + j] + eb[d + j];
}

// ---- layernorm row=512, fp32 -> split bf16 hi/lo planes (swizzled) -------
__global__ __launch_bounds__(256)
void ln_split(const float* __restrict__ X, const float* __restrict__ w,
              const float* __restrict__ bb, u16* __restrict__ hi,
              u16* __restrict__ lo) {
  const int row = blockIdx.x * 4 + (threadIdx.x >> 6);
  const int lane = threadIdx.x & 63;
  const float* xp = X + (size_t)row * 512 + lane * 8;
  float4 a0 = *(const float4*)xp;
  float4 a1 = *(const float4*)(xp + 4);
  float v[8] = {a0.x, a0.y, a0.z, a0.w, a1.x, a1.y, a1.z, a1.w};
  float s = 0.f, sq = 0.f;
  #pragma unroll
  for (int j = 0; j < 8; j++) { s += v[j]; sq += v[j] * v[j]; }
  s = wredf(s); sq = wredf(sq);
  const float mean = s * (1.f / 512.f);
  const float var = fmaxf(sq * (1.f / 512.f) - mean * mean, 0.f);
  const float inv = rsqrtf(var + 1e-5f);
  const float* wp = w + lane * 8;
  const float* bp = bb + lane * 8;
  float o[8];
  #pragma unroll
  for (int j = 0; j < 8; j++)
    o[j] = (v[j] - mean) * inv * wp[j] + bp[j];
  uint2 p0 = splitpk(o[0], o[1]), p1 = splitpk(o[2], o[3]);
  uint2 p2 = splitpk(o[4], o[5]), p3 = splitpk(o[6], o[7]);
  const size_t off = swz_idx(row, lane * 8, 512);
  *(int4*)(hi + off) = make_int4(p0.x, p1.x, p2.x, p3.x);
  *(int4*)(lo + off) = make_int4(p0.y, p1.y, p2.y, p3.y);
}

// ---- plain fp32 -> split planes (swizzled), no norm (head input) ---------
__global__ __launch_bounds__(256)
void split_kernel(const float* __restrict__ X, u16* __restrict__ hi,
                  u16* __restrict__ lo) {
  const int row = blockIdx.x * 4 + (threadIdx.x >> 6);
  const int lane = threadIdx.x & 63;
  const float* xp = X + (size_t)row * 512 + lane * 8;
  float v[8];
  ld4(v, xp); ld4(v + 4, xp + 4);
  uint2 p0 = splitpk(v[0], v[1]), p1 = splitpk(v[2], v[3]);
  uint2 p2 = splitpk(v[4], v[5]), p3 = splitpk(v[6], v[7]);
  const size_t off = swz_idx(row, lane * 8, 512);
  *(int4*)(hi + off) = make_int4(p0.x, p1.x, p2.x, p3.x);
  *(int4*)(lo + off) = make_int4(p0.y, p1.y, p2.y, p3.y);
}

// ---- tiled causal retention attention + fused groupnorm ------------------
// QKV row: [Q(512) K(512) V(1024)], Q/K already rotated+decayed by the GEMM
// epilogue. Epilogue: group-norm over 128 v-dims per (row,h) + affine.
__global__ __launch_bounds__(256)
void attn_fused(const float* __restrict__ QKV, float* __restrict__ Y,
                const float* __restrict__ gw, const float* __restrict__ gb) {
  __shared__ float Qs[64][68];   // [e][s]
  __shared__ float Ks[64][68];   // [e][m]
  __shared__ float At[64][68];   // [m][s]
  const int h = blockIdx.y;
  const int r0 = blockIdx.x * 64;       // chunk-local first row
  const int b = r0 >> 8;
  const int s0 = r0 & 255;
  const int st = s0 >> 6;               // diagonal m-tile index
  const int tid = threadIdx.x;
  const int ty = tid >> 4, tx = tid & 15;

  {  // stage Q transposed
    const int rr = tid >> 2, e0 = (tid & 3) * 16;
    const float* qp = QKV + (size_t)(r0 + rr) * 2048 + h * 64 + e0;
    #pragma unroll
    for (int j = 0; j < 16; j++) Qs[e0 + j][rr] = qp[j];
  }

  float acc2[4][8];
  #pragma unroll
  for (int i = 0; i < 4; i++)
    #pragma unroll
    for (int j = 0; j < 8; j++) acc2[i][j] = 0.f;

  for (int mt = 0; mt <= st; mt++) {
    const int m0 = mt * 64;
    {  // stage K tile transposed
      const int rr = tid >> 2, e0 = (tid & 3) * 16;
      const float* kp = QKV + (size_t)(b * 256 + m0 + rr) * 2048 + 512 + h * 64 + e0;
      #pragma unroll
      for (int j = 0; j < 16; j++) Ks[e0 + j][rr] = kp[j];
    }
    __syncthreads();
    float a1[4][4];
    #pragma unroll
    for (int i = 0; i < 4; i++)
      #pragma unroll
      for (int j = 0; j < 4; j++) a1[i][j] = 0.f;
    #pragma unroll 4
    for (int e = 0; e < 64; e++) {
      float qa[4], kb[4];
      ld4(qa, &Qs[e][ty * 4]);
      ld4(kb, &Ks[e][tx * 4]);
      #pragma unroll
      for (int i = 0; i < 4; i++)
        #pragma unroll
        for (int j = 0; j < 4; j++)
          a1[i][j] = fmaf(qa[i], kb[j], a1[i][j]);
    }
    #pragma unroll
    for (int i = 0; i < 4; i++)
      #pragma unroll
      for (int j = 0; j < 4; j++) {
        float v = a1[i][j];
        if (mt == st && (m0 + tx * 4 + j) > (s0 + ty * 4 + i)) v = 0.f;
        At[tx * 4 + j][ty * 4 + i] = v;
      }
    __syncthreads();
    const float* vp = QKV + (size_t)(b * 256 + m0) * 2048 + 1024 + h * 128 + tx * 8;
    #pragma unroll 4
    for (int m = 0; m < 64; m++) {
      float av[4], vv[8];
      ld4(av, &At[m][ty * 4]);
      ld4(vv, vp);
      ld4(vv + 4, vp + 4);
      vp += 2048;
      #pragma unroll
      for (int i = 0; i < 4; i++)
        #pragma unroll
        for (int j = 0; j < 8; j++)
          acc2[i][j] = fmaf(av[i], vv[j], acc2[i][j]);
    }
    __syncthreads();
  }

  // fused group-norm epilogue: per row, reduce over the 16-lane tx group
  const int vi = h * 128 + tx * 8;
  float gwv[8], gbv[8];
  ld4(gwv, gw + vi); ld4(gwv + 4, gw + vi + 4);
  ld4(gbv, gb + vi); ld4(gbv + 4, gb + vi + 4);
  #pragma unroll
  for (int i = 0; i < 4; i++) {
    float s = 0.f, sq = 0.f;
    #pragma unroll
    for (int j = 0; j < 8; j++) { s += acc2[i][j]; sq += acc2[i][j] * acc2[i][j]; }
    #pragma unroll
    for (int msk = 1; msk <= 8; msk <<= 1) {
      s += __shfl_xor(s, msk, 64);
      sq += __shfl_xor(sq, msk, 64);
    }
    const float mean = s * (1.f / 128.f);
    const float var = fmaxf(sq * (1.f / 128.f) - mean * mean, 0.f);
    const float inv = rsqrtf(var + 1e-5f);
    float o[8];
    #pragma unroll
    for (int j = 0; j < 8; j++)
      o[j] = (acc2[i][j] - mean) * inv * gwv[j] + gbv[j];
    float* yp = Y + (size_t)(r0 + ty * 4 + i) * 1024 + vi;
    st4(yp, o);
    st4(yp + 4, o + 4);
  }
}

// ---- final N=1 dot (fp32) ------------------------------------------------
__global__ __launch_bounds__(256)
void head3_kernel(const float* __restrict__ X, const float* __restrict__ w,
                  const float* __restrict__ b3, float* __restrict__ out) {
  const int row = blockIdx.x * 4 + (threadIdx.x >> 6);
  const int lane = threadIdx.x & 63;
  const float* xp = X + (size_t)row * 512 + lane * 8;
  const float* wp = w + lane * 8;
  float s = 0.f;
  #pragma unroll
  for (int j = 0; j < 8; j++) s += xp[j] * wp[j];
  s = wredf(s);
  if (lane == 0) out[row] = s + b3[0];
}

// ---- weight pre-pack: W[K][N] -> swizzled Bt_hi/Bt_lo [N][K] bf16 --------
__global__ __launch_bounds__(256)
void pack_plain(const float* __restrict__ W, u16* __restrict__ hi,
                u16* __restrict__ lo, int N, int kshift) {
  const int idx = blockIdx.x * 256 + threadIdx.x;   // n*K + k (logical)
  const int K = 1 << kshift;
  const int n = idx >> kshift, k = idx & (K - 1);
  const float v = W[(size_t)k * N + n];
  const unsigned int h = bfh16(v);
  const float l = v - __uint_as_float(h << 16);
  const size_t o = swz_idx(n, k, K);
  hi[o] = (u16)h;
  lo[o] = (u16)bfh16(l);
}

// QKV head-interleaved mapping: col c<512 -> WQ(h,k,e), <1024 -> WK, else WV
__global__ __launch_bounds__(256)
void pack_qkv(const float* __restrict__ WQ, const float* __restrict__ WK,
              const float* __restrict__ WV, u16* __restrict__ hi,
              u16* __restrict__ lo) {
  const int idx = blockIdx.x * 256 + threadIdx.x;   // c*512 + k (logical)
  const int c = idx >> 9, k = idx & 511;
  float v;
  if (c < 512)
    v = WQ[((size_t)(c >> 6) * 512 + k) * 64 + (c & 63)];
  else if (c < 1024)
    v = WK[((size_t)((c - 512) >> 6) * 512 + k) * 64 + ((c - 512) & 63)];
  else
    v = WV[((size_t)((c - 1024) >> 7) * 512 + k) * 128 + ((c - 1024) & 127)];
  const unsigned int h = bfh16(v);
  const float l = v - __uint_as_float(h << 16);
  const size_t o = swz_idx(c, k, 512);
  hi[o] = (u16)h;
  lo[o] = (u16)bfh16(l);
}

// ---- bf16x3 MFMA GEMM, dbuf gload_lds + counted vmcnt + XCD swizzle ------
// K-step t: issue stage(t+1) -> s_waitcnt vmcnt(8) (t's loads drained,
// t+1's 8 stay in flight ACROSS the barrier) -> s_barrier -> frag reads +
// 48 MFMA -> s_barrier.  Last step: vmcnt(0).
// Block remap: bijective XCD-chunk, n-major, so each XCD keeps its B-panels
// L2-resident while A streams (T1).
// EPI 0: store    1: silu(acc)*aux     2: acc+aux
//     3: gelu(acc+bias)   4: acc+bias+aux   5: w0*sin(acc+b)+w1*cos(acc+b)
//     6: QKV xpos-rotation + retention decay via rtab (V pass-through)
// OSPLIT 0: fp32 C.  1: swizzled split bf16 planes Ch/Cl.
template<int EPI, int OSPLIT>
__global__ __launch_bounds__(256, 2)
void gemm_lds(const u16* __restrict__ Agh, const u16* __restrict__ Agl,
              const u16* __restrict__ Bh, const u16* __restrict__ Bl,
              float* __restrict__ C, u16* __restrict__ Ch, u16* __restrict__ Cl,
              const int N, const int K,
              const float* __restrict__ bias, const float* __restrict__ aux,
              const float* __restrict__ wave2, const float* __restrict__ rtab) {
  __shared__ __align__(16) u16 S[2][4][128][32];   // dbuf x {Ah,Al,Bh,Bl}
  const int tid = threadIdx.x;
  const int lane = tid & 63;
  const int wave = tid >> 6;
  const int wr = (wave >> 1) * 64, wc = (wave & 1) * 64;

  // XCD-chunked bijective remap, n-major logical order (T1)
  int bx = blockIdx.x, by = blockIdx.y;
  {
    const int gx = gridDim.x, gy = gridDim.y;
    const int nwg = gx * gy;
    if ((nwg & 7) == 0) {
      const int id = by * gx + bx;          // dispatch order (x fastest)
      const int q = nwg >> 3;
      const int L = (id & 7) * q + (id >> 3);
      bx = L / gy;                          // n-panel (contiguous per XCD)
      by = L - bx * gy;                     // m-panel
    }
  }
  const int m0 = by * 128, n0 = bx * 128;

  const int fm = lane & 15;
  const int q = lane >> 4;            // logical 16B chunk 0..3

  const u16* pb;
  if (wave == 0)      pb = Agh + (size_t)m0 * K;
  else if (wave == 1) pb = Agl + (size_t)m0 * K;
  else if (wave == 2) pb = Bh + (size_t)n0 * K;
  else                pb = Bl + (size_t)n0 * K;
  const u16* src0 = pb + (size_t)(lane >> 2) * K + (lane & 3) * 8;

  f32x4 acc[4][4];
  #pragma unroll
  for (int i = 0; i < 4; i++)
    #pragma unroll
    for (int j = 0; j < 4; j++)
      acc[i][j] = (f32x4){0.f, 0.f, 0.f, 0.f};

  {  // prologue: stage tile 0 into buf 0 (full drain via __syncthreads)
    u16* dst = &S[0][wave][0][0];
    #pragma unroll
    for (int i = 0; i < 8; i++)
      gload_lds16(src0 + (size_t)(i * 16) * K, dst + i * 512);
  }
  __syncthreads();

  for (int kt = 0; kt < K; kt += 32) {
    const int cur = (kt >> 5) & 1;
    if (kt + 32 < K) {  // issue next tile; keep its 8 loads in flight
      u16* dst = &S[cur ^ 1][wave][0][0];
      const u16* s = src0 + kt + 32;
      #pragma unroll
      for (int i = 0; i < 8; i++)
        gload_lds16(s + (size_t)(i * 16) * K, dst + i * 512);
      asm volatile("s_waitcnt vmcnt(8)" ::: "memory");
    } else {
      asm volatile("s_waitcnt vmcnt(0)" ::: "memory");
    }
    __builtin_amdgcn_sched_barrier(0);
    __builtin_amdgcn_s_barrier();
    __builtin_amdgcn_sched_barrier(0);

    bf16x8 avh[4], avl[4];
    #pragma unroll
    for (int mf = 0; mf < 4; mf++) {
      const int m = wr + mf * 16 + fm;
      const int c = (q ^ ((m >> 1) & 3)) * 8;   // swizzled read
      avh[mf] = *(const bf16x8*)&S[cur][0][m][c];
      avl[mf] = *(const bf16x8*)&S[cur][1][m][c];
    }
    #pragma unroll
    for (int nf = 0; nf < 4; nf++) {
      const int n = wc + nf * 16 + fm;
      const int c = (q ^ ((n >> 1) & 3)) * 8;
      bf16x8 bh = *(const bf16x8*)&S[cur][2][n][c];
      bf16x8 bl = *(const bf16x8*)&S[cur][3][n][c];
      #pragma unroll
      for (int mf = 0; mf < 4; mf++) {
        acc[mf][nf] = __builtin_amdgcn_mfma_f32_16x16x32_bf16(avh[mf], bh, acc[mf][nf], 0, 0, 0);
        acc[mf][nf] = __builtin_amdgcn_mfma_f32_16x16x32_bf16(avl[mf], bh, acc[mf][nf], 0, 0, 0);
        acc[mf][nf] = __builtin_amdgcn_mfma_f32_16x16x32_bf16(avh[mf], bl, acc[mf][nf], 0, 0, 0);
      }
    }
    __builtin_amdgcn_sched_barrier(0);
    __builtin_amdgcn_s_barrier();
  }

  // epilogue: D frag: col = lane&15, row = (lane>>4)*4 + r
  const int r0 = m0 + wr + (lane >> 4) * 4;
  const int c0 = n0 + wc + fm;
  #pragma unroll
  for (int mf = 0; mf < 4; mf++) {
    #pragma unroll
    for (int nf = 0; nf < 4; nf++) {
      const int col = c0 + nf * 16;
      #pragma unroll
      for (int r = 0; r < 4; r++) {
        const int row = r0 + mf * 16 + r;
        const size_t idx = (size_t)row * N + col;   // logical (C, aux)
        float v = acc[mf][nf][r];
        float o;
        if constexpr (EPI == 0) {
          o = v;
        } else if constexpr (EPI == 1) {
          const float g = v / (1.f + expf(-v));
          o = g * aux[idx];
        } else if constexpr (EPI == 2) {
          o = v + aux[idx];
        } else if constexpr (EPI == 3) {
          v += bias[col];
          o = 0.5f * v * (1.f + erff(v * 0.70710678118654752f));
        } else if constexpr (EPI == 4) {
          o = v + bias[col] + aux[idx];
        } else if constexpr (EPI == 5) {
          v += bias[col];
          o = wave2[0] * sinf(v) + wave2[1] * cosf(v);
        } else {
          // EPI 6: xpos rotation + decay for Q/K cols; V pass-through.
          // partner col = col^1 lives in lane^1, same row/regs.
          const float p = __shfl_xor(v, 1, 64);
          if (col < 1024) {               // wave-uniform branch
            const int s = row & 255;
            const int cc = col & 511;
            const int hh = cc >> 6;
            const int ii = (cc & 63) >> 1;
            const bool isK = col >= 512;
            const float2 cs2 = *(const float2*)(
                rtab + (isK ? 16384 : 0) + ((size_t)s * 32 + ii) * 2);
            const float g = rtab[(isK ? 34816 : 32768) + hh * 256 + s];
            o = ((col & 1) ? (v * cs2.x + p * cs2.y)
                           : (v * cs2.x - p * cs2.y)) * g;
          } else {
            o = v;
          }
        }
        if constexpr (OSPLIT == 0) {
          C[idx] = o;
        } else {
          const size_t sidx = swz_idx(row, col, N);
          const unsigned int hb = bfh16(o);
          Ch[sidx] = (u16)hb;
          Cl[sidx] = (u16)bfh16(o - __uint_as_float(hb << 16));
        }
      }
    }
  }
}

// ---- launch --------------------------------------------------------------

extern "C" void kernel_launch(void* const* d_in, const int* in_sizes, int n_in,
                              void* d_out, int out_size, void* d_ws, size_t ws_size,
                              hipStream_t stream) {
  (void)in_sizes; (void)n_in; (void)out_size;
  const float* x    = (const float*)d_in[0];
  const float* t    = (const float*)d_in[1];
  const float* embW = (const float*)d_in[2];
  const float* embB = (const float*)d_in[3];
  const float* ln1w = (const float*)d_in[4];
  const float* ln1b = (const float*)d_in[5];
  const float* ln2w = (const float*)d_in[6];
  const float* ln2b = (const float*)d_in[7];
  const float* WQ   = (const float*)d_in[8];
  const float* WK   = (const float*)d_in[9];
  const float* WV   = (const float*)d_in[10];
  const float* WG   = (const float*)d_in[11];
  const float* WO   = (const float*)d_in[12];
  const float* gnw  = (const float*)d_in[13];
  const float* gnb  = (const float*)d_in[14];
  const float* f1W  = (const float*)d_in[15];
  const float* f1b  = (const float*)d_in[16];
  const float* f2W  = (const float*)d_in[17];
  const float* f2bp = (const float*)d_in[18];
  const float* h1W  = (const float*)d_in[19];
  const float* h1b  = (const float*)d_in[20];
  const float* wvw  = (const float*)d_in[21];
  const float* h2W  = (const float*)d_in[22];
  const float* h2b  = (const float*)d_in[23];
  const float* h3W  = (const float*)d_in[24];
  const float* h3b  = (const float*)d_in[25];

  // ---- packed-weight area (bf16 hi/lo, swizzled [N][K]) ----
  u16* P = (u16*)d_ws;
  const size_t SQKV = 2048 * 512, SWG = 1024 * 512, SWO = 512 * 1024;
  const size_t SF1 = 128 * 512, SF2 = 512 * 128;
  const size_t PERL = 2 * (SQKV + SWG + SWO + SF1 + SF2);
  const size_t HOFF = 4 * PERL;                 // heads after layers
  const size_t PACK_BYTES = (HOFF + 4 * 512 * 512) * 2;  // = 37748736
  const size_t TAB_BYTES = 36864 * 4;           // rotation/decay tables

  u16* h1h = P + HOFF;
  u16* h1l = h1h + 512 * 512;
  u16* h2h = h1l + 512 * 512;
  u16* h2l = h2h + 512 * 512;
  float* RT = (float*)((char*)d_ws + PACK_BYTES);

  const dim3 blk(256);

  // tables + pack all weights once
  tab_kernel<<<dim3(80), blk, 0, stream>>>(RT);
  for (int l = 0; l < 4; l++) {
    u16* qkvh = P + l * PERL;
    u16* qkvl = qkvh + SQKV;
    u16* wgh  = qkvl + SQKV;
    u16* wgl  = wgh + SWG;
    u16* woh  = wgl + SWG;
    u16* wol  = woh + SWO;
    u16* f1h  = wol + SWO;
    u16* f1l  = f1h + SF1;
    u16* f2h  = f1l + SF1;
    u16* f2l  = f2h + SF2;
    pack_qkv<<<dim3(SQKV / 256), blk, 0, stream>>>(
        WQ + (size_t)l * 262144, WK + (size_t)l * 262144,
        WV + (size_t)l * 524288, qkvh, qkvl);
    pack_plain<<<dim3(SWG / 256), blk, 0, stream>>>(WG + (size_t)l * 524288, wgh, wgl, 1024, 9);
    pack_plain<<<dim3(SWO / 256), blk, 0, stream>>>(WO + (size_t)l * 524288, woh, wol, 512, 10);
    pack_plain<<<dim3(SF1 / 256), blk, 0, stream>>>(f1W + (size_t)l * 65536, f1h, f1l, 128, 9);
    pack_plain<<<dim3(SF2 / 256), blk, 0, stream>>>(f2W + (size_t)l * 65536, f2h, f2l, 512, 7);
  }
  pack_plain<<<dim3(1024), blk, 0, stream>>>(h1W, h1h, h1l, 512, 9);
  pack_plain<<<dim3(1024), blk, 0, stream>>>(h2W, h2h, h2l, 512, 9);

  // ---- batch-chunking so fp32 activations fit after pack+tables ----
  const size_t BASE = PACK_BYTES + TAB_BYTES;
  int NC = 1;
  while (NC < 256) {
    const size_t R = 65536u / NC;
    if (BASE + R * 18432 + 4096 <= ws_size) break;
    NC <<= 1;
  }
  const int R = 65536 / NC;   // rows per chunk (multiple of 256)

  float* Xf   = (float*)((char*)d_ws + BASE);  // R x 512 residual
  float* Xn   = Xf  + (size_t)R * 512;   // R x 512   slot: LN planes
  float* QKVb = Xn  + (size_t)R * 512;   // R x 2048  QKV fp32; later GY planes
  float* Yb   = QKVb + (size_t)R * 2048; // R x 1024  Y fp32 / mid planes / H1
  float* Yr   = Yb  + (size_t)R * 1024;  // R x 512   Yr residual / H2 fp32

  u16* Xnh = (u16*)Xn;           u16* Xnl = Xnh + (size_t)R * 512;
  u16* GYh = (u16*)QKVb;         u16* GYl = GYh + (size_t)R * 1024;
  u16* midh = (u16*)Yb;          u16* midl = midh + (size_t)R * 128;
  u16* H1h = (u16*)Yb;           u16* H1l = H1h + (size_t)R * 512;

  for (int c = 0; c < NC; c++) {
    const size_t off = (size_t)c * R;
    embed_kernel<<<dim3(R / 4), blk, 0, stream>>>(x + off, t + off, embW, embB, Xf);

    for (int l = 0; l < 4; l++) {
      u16* qkvh = P + l * PERL;
      u16* qkvl = qkvh + SQKV;
      u16* wgh  = qkvl + SQKV;
      u16* wgl  = wgh + SWG;
      u16* woh  = wgl + SWG;
      u16* wol  = woh + SWO;
      u16* f1h  = wol + SWO;
      u16* f1l  = f1h + SF1;
      u16* f2h  = f1l + SF1;
      u16* f2l  = f2h + SF2;

      ln_split<<<dim3(R / 4), blk, 0, stream>>>(Xf, ln1w + l * 512, ln1b + l * 512, Xnh, Xnl);
      // QKV = Xn @ [WQ|WK|WV][l], rotation+decay fused in epilogue
      gemm_lds<6, 0><<<dim3(16, R / 128), blk, 0, stream>>>(
          Xnh, Xnl, qkvh, qkvl, QKVb, nullptr, nullptr,
          2048, 512, nullptr, nullptr, nullptr, RT);
      // causal retention attention + fused groupnorm
      attn_fused<<<dim3(R / 64, 8), blk, 0, stream>>>(
          QKVb, Yb, gnw + l * 1024, gnb + l * 1024);
      // GY = silu(Xn @ WG[l]) * Y  -> split planes in QKVb (QKV dead)
      gemm_lds<1, 1><<<dim3(8, R / 128), blk, 0, stream>>>(
          Xnh, Xnl, wgh, wgl, nullptr, GYh, GYl,
          1024, 512, nullptr, Yb, nullptr, nullptr);
      // Yr = GY @ WO[l] + X
      gemm_lds<2, 0><<<dim3(4, R / 128), blk, 0, stream>>>(
          GYh, GYl, woh, wol, Yr, nullptr, nullptr,
          512, 1024, nullptr, Xf, nullptr, nullptr);
      ln_split<<<dim3(R / 4), blk, 0, stream>>>(Yr, ln2w + l * 512, ln2b + l * 512, Xnh, Xnl);
      // mid = gelu(Xn @ f1[l] + b1)  -> split planes in Yb
      gemm_lds<3, 1><<<dim3(1, R / 128), blk, 0, stream>>>(
          Xnh, Xnl, f1h, f1l, nullptr, midh, midl,
          128, 512, f1b + l * 128, nullptr, nullptr, nullptr);
      // X = mid @ f2[l] + b2 + Yr
      gemm_lds<4, 0><<<dim3(4, R / 128), blk, 0, stream>>>(
          midh, midl, f2h, f2l, Xf, nullptr, nullptr,
          512, 128, f2bp + l * 512, Yr, nullptr, nullptr);
    }

    // head: split Xf once, then gemm_lds all the way
    split_kernel<<<dim3(R / 4), blk, 0, stream>>>(Xf, Xnh, Xnl);
    gemm_lds<5, 1><<<dim3(4, R / 128), blk, 0, stream>>>(
        Xnh, Xnl, h1h, h1l, nullptr, H1h, H1l,
        512, 512, h1b, nullptr, wvw, nullptr);
    gemm_lds<5, 0><<<dim3(4, R / 128), blk, 0, stream>>>(
        H1h, H1l, h2h, h2l, Yr, nullptr, nullptr,
        512, 512, h2b, nullptr, wvw + 2, nullptr);
    head3_kernel<<<dim3(R / 4), blk, 0, stream>>>(
        Yr, h3W, h3b, (float*)d_out + off);
  }
}